// Round 1
// baseline (816.349 us; speedup 1.0000x reference)
//
#include <hip/hip_runtime.h>
#include <cstdint>
#include <cstddef>

#define NN 20000
#define EE 320000
#define TE (EE + NN)      // edges + self loops
#define NG 16
#define DIN 256
#define HID 64
#define HEADS 4
#define LN_EPS 1e-5f
#define SLOPE 0.2f

// ---------------------------------------------------------------- CSR build
__global__ void count_kernel(const int* __restrict__ ei, int* __restrict__ counts,
                             const int* __restrict__ batch, int* __restrict__ gcnt) {
    int i = blockIdx.x * blockDim.x + threadIdx.x;
    if (i < TE) {
        int d = (i < EE) ? ei[EE + i] : (i - EE);
        atomicAdd(&counts[d], 1);
    }
    if (i < NN) {
        atomicAdd(&gcnt[batch[i]], 1);
    }
}

__global__ void scan_kernel(const int* __restrict__ cnt, int* __restrict__ off,
                            int* __restrict__ cursor) {
    __shared__ int buf[1024];
    __shared__ int carry_s;
    int t = threadIdx.x;
    if (t == 0) { carry_s = 0; off[0] = 0; }
    __syncthreads();
    for (int base = 0; base < NN; base += 1024) {
        int i = base + t;
        int v = (i < NN) ? cnt[i] : 0;
        buf[t] = v;
        __syncthreads();
        for (int s = 1; s < 1024; s <<= 1) {
            int add = (t >= s) ? buf[t - s] : 0;
            __syncthreads();
            buf[t] += add;
            __syncthreads();
        }
        int inc = buf[t] + carry_s;
        if (i < NN) { off[i + 1] = inc; cursor[i] = inc - v; }
        __syncthreads();
        if (t == 1023) carry_s = inc;
        __syncthreads();
    }
}

__global__ void csr_fill_kernel(const int* __restrict__ ei, int* __restrict__ cursor,
                                int* __restrict__ csr_src) {
    int i = blockIdx.x * blockDim.x + threadIdx.x;
    if (i >= TE) return;
    int s, d;
    if (i < EE) { s = ei[i]; d = ei[EE + i]; }
    else        { s = i - EE; d = s; }
    int pos = atomicAdd(&cursor[d], 1);
    csr_src[pos] = s;
}

__global__ void gstart_kernel(const int* __restrict__ gcnt, int* __restrict__ gstart) {
    if (threadIdx.x == 0 && blockIdx.x == 0) {
        int s = 0;
        for (int g = 0; g < NG; g++) { gstart[g] = s; s += gcnt[g]; }
        gstart[NG] = s;
    }
}

// ---------------------------------------------------------------- GEMM (fp32)
// C[M,Nc] = A[M,K] * B[K,Nc].  BM=BN=64, BK=16, 256 threads, 4x4 microtile.
#define BM 64
#define BN 64
#define BK 16
__global__ __launch_bounds__(256) void gemm_kernel(const float* __restrict__ A,
                                                   const float* __restrict__ B,
                                                   float* __restrict__ C,
                                                   int M, int K, int Nc) {
    __shared__ float As[BK][BM + 1];
    __shared__ float Bs[BK][BN + 1];
    int bm = blockIdx.x * BM;
    int bn = blockIdx.y * BN;
    int t = threadIdx.x;
    int tx = t & 15, ty = t >> 4;
    float acc[4][4] = {};
    int ar = t >> 2, ac = (t & 3) * 4;     // A tile: 64 rows x 16 cols (float4)
    int br = t >> 4, bc = (t & 15) * 4;    // B tile: 16 rows x 64 cols (float4)
    for (int k0 = 0; k0 < K; k0 += BK) {
        float4 av = make_float4(0.f, 0.f, 0.f, 0.f);
        int arow = bm + ar;
        if (arow < M)
            av = *reinterpret_cast<const float4*>(&A[(size_t)arow * K + k0 + ac]);
        As[ac + 0][ar] = av.x; As[ac + 1][ar] = av.y;
        As[ac + 2][ar] = av.z; As[ac + 3][ar] = av.w;
        float4 bv = *reinterpret_cast<const float4*>(&B[(size_t)(k0 + br) * Nc + bn + bc]);
        Bs[br][bc + 0] = bv.x; Bs[br][bc + 1] = bv.y;
        Bs[br][bc + 2] = bv.z; Bs[br][bc + 3] = bv.w;
        __syncthreads();
#pragma unroll
        for (int kk = 0; kk < BK; kk++) {
            float a[4], b[4];
#pragma unroll
            for (int i = 0; i < 4; i++) a[i] = As[kk][ty * 4 + i];
#pragma unroll
            for (int j = 0; j < 4; j++) b[j] = Bs[kk][tx * 4 + j];
#pragma unroll
            for (int i = 0; i < 4; i++)
#pragma unroll
                for (int j = 0; j < 4; j++) acc[i][j] += a[i] * b[j];
        }
        __syncthreads();
    }
#pragma unroll
    for (int i = 0; i < 4; i++) {
        int row = bm + ty * 4 + i;
        if (row < M) {
#pragma unroll
            for (int j = 0; j < 4; j++)
                C[(size_t)row * Nc + bn + tx * 4 + j] = acc[i][j];
        }
    }
}

// ---------------------------------------------------------------- attention scores
// es[n,h] = sum_d h[n,h,d]*asrc[h,d];  ed likewise. block = F threads (F = nheads*64)
__global__ void attn_score_kernel(const float* __restrict__ h,
                                  const float* __restrict__ asrc,
                                  const float* __restrict__ adst,
                                  float* __restrict__ es, float* __restrict__ ed,
                                  int F, int nheads) {
    int n = blockIdx.x;
    int t = threadIdx.x;
    float v = h[(size_t)n * F + t];
    float ps = v * asrc[t];
    float pd = v * adst[t];
    for (int s = 32; s > 0; s >>= 1) {
        ps += __shfl_down(ps, s);
        pd += __shfl_down(pd, s);
    }
    if ((t & 63) == 0) {
        int hd = t >> 6;
        es[n * nheads + hd] = ps;
        ed[n * nheads + hd] = pd;
    }
}

// ---------------------------------------------------------------- GAT aggregation + LN + relu + residual  (heads=4, F=256)
__global__ __launch_bounds__(256) void gat_agg_ln_kernel(
    const float* __restrict__ h, const float* __restrict__ es, const float* __restrict__ ed,
    const int* __restrict__ off, const int* __restrict__ csr,
    const float* __restrict__ bias, const float* __restrict__ gamma, const float* __restrict__ beta,
    const float* __restrict__ resid, float* __restrict__ xout) {
    int n = blockIdx.x;
    int t = threadIdx.x;
    int head = t >> 6, lane = t & 63;
    int j0 = off[n], j1 = off[n + 1];
    float edn = ed[n * HEADS + head];

    // per-head max (strided over edges, wave reduce)
    float mloc = -INFINITY;
    for (int j = j0 + lane; j < j1; j += 64) {
        int s = csr[j];
        float e = es[s * HEADS + head] + edn;
        e = (e >= 0.f) ? e : SLOPE * e;
        mloc = fmaxf(mloc, e);
    }
    for (int s = 32; s > 0; s >>= 1) mloc = fmaxf(mloc, __shfl_xor(mloc, s));
    // per-head sum of exp
    float ssum = 0.f;
    for (int j = j0 + lane; j < j1; j += 64) {
        int s = csr[j];
        float e = es[s * HEADS + head] + edn;
        e = (e >= 0.f) ? e : SLOPE * e;
        ssum += __expf(e - mloc);
    }
    for (int s = 32; s > 0; s >>= 1) ssum += __shfl_xor(ssum, s);

    // accumulate weighted features (thread owns dim t = head*64+lane)
    float acc = 0.f;
    for (int j = j0; j < j1; j++) {
        int s = csr[j];
        float e = es[s * HEADS + head] + edn;
        e = (e >= 0.f) ? e : SLOPE * e;
        float w = __expf(e - mloc);
        acc += w * h[(size_t)s * 256 + t];
    }
    float v = acc / (ssum + 1e-16f) + bias[t];

    // LayerNorm over 256 dims
    __shared__ float red[8];
    float ls = v, lq = v * v;
    for (int s = 32; s > 0; s >>= 1) { ls += __shfl_xor(ls, s); lq += __shfl_xor(lq, s); }
    if (lane == 0) { red[head] = ls; red[4 + head] = lq; }
    __syncthreads();
    float tot = red[0] + red[1] + red[2] + red[3];
    float totq = red[4] + red[5] + red[6] + red[7];
    float mu = tot * (1.0f / 256.0f);
    float var = totq * (1.0f / 256.0f) - mu * mu;
    float y = (v - mu) * rsqrtf(var + LN_EPS) * gamma[t] + beta[t];
    y = fmaxf(y, 0.f);
    xout[(size_t)n * 256 + t] = y + resid[(size_t)n * 256 + t];
}

// ---------------------------------------------------------------- final GAT (heads=1, F=64) + LN + relu
__global__ __launch_bounds__(64) void gat_final_kernel(
    const float* __restrict__ h, const float* __restrict__ es, const float* __restrict__ ed,
    const int* __restrict__ off, const int* __restrict__ csr,
    const float* __restrict__ bias, const float* __restrict__ gamma, const float* __restrict__ beta,
    float* __restrict__ xout) {
    int n = blockIdx.x;
    int t = threadIdx.x;
    int j0 = off[n], j1 = off[n + 1];
    float edn = ed[n];
    float mloc = -INFINITY;
    for (int j = j0 + t; j < j1; j += 64) {
        int s = csr[j];
        float e = es[s] + edn;
        e = (e >= 0.f) ? e : SLOPE * e;
        mloc = fmaxf(mloc, e);
    }
    for (int s = 32; s > 0; s >>= 1) mloc = fmaxf(mloc, __shfl_xor(mloc, s));
    float ssum = 0.f;
    for (int j = j0 + t; j < j1; j += 64) {
        int s = csr[j];
        float e = es[s] + edn;
        e = (e >= 0.f) ? e : SLOPE * e;
        ssum += __expf(e - mloc);
    }
    for (int s = 32; s > 0; s >>= 1) ssum += __shfl_xor(ssum, s);
    float acc = 0.f;
    for (int j = j0; j < j1; j++) {
        int s = csr[j];
        float e = es[s] + edn;
        e = (e >= 0.f) ? e : SLOPE * e;
        acc += __expf(e - mloc) * h[(size_t)s * 64 + t];
    }
    float v = acc / (ssum + 1e-16f) + bias[t];
    float ls = v, lq = v * v;
    for (int s = 32; s > 0; s >>= 1) { ls += __shfl_xor(ls, s); lq += __shfl_xor(lq, s); }
    float mu = ls * (1.0f / 64.0f);
    float var = lq * (1.0f / 64.0f) - mu * mu;
    float y = (v - mu) * rsqrtf(var + LN_EPS) * gamma[t] + beta[t];
    xout[(size_t)n * 64 + t] = fmaxf(y, 0.f);
}

// ---------------------------------------------------------------- pooling
__global__ __launch_bounds__(256) void pool_partial_kernel(
    const float* __restrict__ x, const int* __restrict__ gstart,
    float* __restrict__ gsum, unsigned* __restrict__ gmax) {
    int g = blockIdx.x, sp = blockIdx.y;
    int r0 = gstart[g], r1 = gstart[g + 1];
    int t = threadIdx.x, d = t & 63, rg = t >> 6;
    float sum = 0.f, mx = 0.f;   // x >= 0 post-relu, so 0 is a safe max identity
    for (int r = r0 + sp * 4 + rg; r < r1; r += 32) {
        float v = x[(size_t)r * 64 + d];
        sum += v;
        mx = fmaxf(mx, v);
    }
    __shared__ float S[256], M[256];
    S[t] = sum; M[t] = mx;
    __syncthreads();
    if (t < 64) {
        float s4 = S[t] + S[t + 64] + S[t + 128] + S[t + 192];
        float m4 = fmaxf(fmaxf(M[t], M[t + 64]), fmaxf(M[t + 128], M[t + 192]));
        atomicAdd(&gsum[g * 64 + t], s4);
        atomicMax(&gmax[g * 64 + t], __float_as_uint(m4));
    }
}

__global__ void pool_final_kernel(const float* __restrict__ gsum,
                                  const unsigned* __restrict__ gmax,
                                  const int* __restrict__ gcnt,
                                  float* __restrict__ pout) {
    int g = blockIdx.x, d = threadIdx.x;
    float c = (float)gcnt[g];
    c = fmaxf(c, 1.0f);
    pout[g * 128 + d] = gsum[g * 64 + d] / c;
    pout[g * 128 + 64 + d] = __uint_as_float(gmax[g * 64 + d]);
}

// ---------------------------------------------------------------- launch
extern "C" void kernel_launch(void* const* d_in, const int* in_sizes, int n_in,
                              void* d_out, int out_size, void* d_ws, size_t ws_size,
                              hipStream_t stream) {
    const float* node_x = (const float*)d_in[0];
    const int*   ei     = (const int*)d_in[1];
    const int*   batch  = (const int*)d_in[2];
    const float* W1  = (const float*)d_in[3];
    const float* as1 = (const float*)d_in[4];
    const float* ad1 = (const float*)d_in[5];
    const float* b1  = (const float*)d_in[6];
    const float* g1  = (const float*)d_in[7];
    const float* be1 = (const float*)d_in[8];
    const float* W2  = (const float*)d_in[9];
    const float* as2 = (const float*)d_in[10];
    const float* ad2 = (const float*)d_in[11];
    const float* b2  = (const float*)d_in[12];
    const float* g2  = (const float*)d_in[13];
    const float* be2 = (const float*)d_in[14];
    const float* Wf  = (const float*)d_in[15];
    const float* asf = (const float*)d_in[16];
    const float* adf = (const float*)d_in[17];
    const float* bf  = (const float*)d_in[18];
    const float* gf  = (const float*)d_in[19];
    const float* bef = (const float*)d_in[20];
    float* out = (float*)d_out;

    char* w = (char*)d_ws;
    auto alloc = [&](size_t bytes) -> void* {
        void* p = (void*)w;
        w += (bytes + 255) & ~(size_t)255;
        return p;
    };
    float*    h      = (float*)alloc((size_t)NN * 256 * 4);
    float*    x1     = (float*)alloc((size_t)NN * 256 * 4);
    float*    x2     = (float*)alloc((size_t)NN * 256 * 4);
    float*    es     = (float*)alloc((size_t)NN * HEADS * 4);
    float*    ed     = (float*)alloc((size_t)NN * HEADS * 4);
    int*      counts = (int*)alloc((size_t)NN * 4);
    int*      off    = (int*)alloc((size_t)(NN + 1) * 4);
    int*      cursor = (int*)alloc((size_t)NN * 4);
    int*      csr    = (int*)alloc((size_t)TE * 4);
    float*    gsum   = (float*)alloc((size_t)NG * 64 * 4);
    unsigned* gmax   = (unsigned*)alloc((size_t)NG * 64 * 4);
    int*      gcnt   = (int*)alloc((size_t)NG * 4);
    int*      gstart = (int*)alloc((size_t)(NG + 1) * 4);

    // zero the accumulators/counters (ws is poisoned 0xAA before every call)
    hipMemsetAsync(counts, 0, (size_t)NN * 4, stream);
    hipMemsetAsync(gcnt, 0, (size_t)NG * 4, stream);
    hipMemsetAsync(gsum, 0, (size_t)NG * 64 * 4, stream);
    hipMemsetAsync(gmax, 0, (size_t)NG * 64 * 4, stream);

    // CSR build (shared by all 3 layers)
    count_kernel<<<(TE + 255) / 256, 256, 0, stream>>>(ei, counts, batch, gcnt);
    scan_kernel<<<1, 1024, 0, stream>>>(counts, off, cursor);
    csr_fill_kernel<<<(TE + 255) / 256, 256, 0, stream>>>(ei, cursor, csr);
    gstart_kernel<<<1, 1, 0, stream>>>(gcnt, gstart);

    dim3 gemm_grid_big((NN + BM - 1) / BM, 256 / BN);
    dim3 gemm_grid_fin((NN + BM - 1) / BM, 64 / BN);

    // ---- layer 1
    gemm_kernel<<<gemm_grid_big, 256, 0, stream>>>(node_x, W1, h, NN, 256, 256);
    attn_score_kernel<<<NN, 256, 0, stream>>>(h, as1, ad1, es, ed, 256, HEADS);
    gat_agg_ln_kernel<<<NN, 256, 0, stream>>>(h, es, ed, off, csr, b1, g1, be1, node_x, x1);
    // ---- layer 2
    gemm_kernel<<<gemm_grid_big, 256, 0, stream>>>(x1, W2, h, NN, 256, 256);
    attn_score_kernel<<<NN, 256, 0, stream>>>(h, as2, ad2, es, ed, 256, HEADS);
    gat_agg_ln_kernel<<<NN, 256, 0, stream>>>(h, es, ed, off, csr, b2, g2, be2, x1, x2);
    // ---- final layer
    gemm_kernel<<<gemm_grid_fin, 256, 0, stream>>>(x2, Wf, h, NN, 256, 64);
    attn_score_kernel<<<NN, 64, 0, stream>>>(h, asf, adf, es, ed, 64, 1);
    gat_final_kernel<<<NN, 64, 0, stream>>>(h, es, ed, off, csr, bf, gf, bef, out);
    // ---- pooling
    pool_partial_kernel<<<dim3(NG, 8), 256, 0, stream>>>(out, gstart, gsum, gmax);
    pool_final_kernel<<<NG, 64, 0, stream>>>(gsum, gmax, gcnt, out + (size_t)NN * 64);
}

// Round 2
// 474.211 us; speedup vs baseline: 1.7215x; 1.7215x over previous
//
#include <hip/hip_runtime.h>
#include <cstdint>
#include <cstddef>

#define NN 20000
#define EE 320000
#define TE (EE + NN)      // edges + self loops
#define NG 16
#define HEADS 4
#define LN_EPS 1e-5f
#define SLOPE 0.2f

typedef __attribute__((ext_vector_type(8))) short bfx8;
typedef __attribute__((ext_vector_type(4))) float f32x4;

__device__ __forceinline__ short f2bf(float f) {
    unsigned u = __float_as_uint(f);
    u += 0x7FFFu + ((u >> 16) & 1u);   // RNE
    return (short)(u >> 16);
}

// ---------------------------------------------------------------- CSR build
__global__ void deg_kernel(const int* __restrict__ ei, int* __restrict__ counts) {
    int i = blockIdx.x * blockDim.x + threadIdx.x;
    if (i >= TE) return;
    int d = (i < EE) ? ei[EE + i] : (i - EE);
    atomicAdd(&counts[d], 1);
}

__global__ __launch_bounds__(256) void bsum_kernel(const int* __restrict__ cnt,
                                                   int* __restrict__ bsum) {
    int b = blockIdx.x;
    int i = b * 256 + threadIdx.x;
    int v = (i < NN) ? cnt[i] : 0;
    for (int s = 32; s > 0; s >>= 1) v += __shfl_down(v, s);
    __shared__ int ws4[4];
    int lane = threadIdx.x & 63, w = threadIdx.x >> 6;
    if (lane == 0) ws4[w] = v;
    __syncthreads();
    if (threadIdx.x == 0) bsum[b] = ws4[0] + ws4[1] + ws4[2] + ws4[3];
}

__global__ void bscan_kernel(const int* __restrict__ bsum, int* __restrict__ boff, int nb) {
    __shared__ int s[128];
    int t = threadIdx.x;
    int v = (t < nb) ? bsum[t] : 0;
    s[t] = v;
    __syncthreads();
    for (int st = 1; st < 128; st <<= 1) {
        int a = (t >= st) ? s[t - st] : 0;
        __syncthreads();
        s[t] += a;
        __syncthreads();
    }
    if (t < nb) boff[t] = s[t] - v;   // exclusive
}

__global__ __launch_bounds__(256) void offsets_kernel(const int* __restrict__ cnt,
                                                      const int* __restrict__ boff,
                                                      int* __restrict__ off,
                                                      int* __restrict__ cursor) {
    int b = blockIdx.x, t = threadIdx.x;
    int i = b * 256 + t;
    int v = (i < NN) ? cnt[i] : 0;
    int lane = t & 63, w = t >> 6;
    int x = v;
    for (int s = 1; s < 64; s <<= 1) {
        int u = __shfl_up(x, s);
        if (lane >= s) x += u;
    }
    __shared__ int wsum[4];
    if (lane == 63) wsum[w] = x;
    __syncthreads();
    int pre = 0;
    for (int k = 0; k < w; k++) pre += wsum[k];
    int excl = (x + pre - v) + boff[b];
    if (i < NN) { cursor[i] = excl; off[i] = excl; }
    if (i == NN - 1) off[NN] = excl + v;
}

__global__ void csr_fill_kernel(const int* __restrict__ ei, int* __restrict__ cursor,
                                int* __restrict__ csr_src) {
    int i = blockIdx.x * blockDim.x + threadIdx.x;
    if (i >= TE) return;
    int s, d;
    if (i < EE) { s = ei[i]; d = ei[EE + i]; }
    else        { s = i - EE; d = s; }
    int pos = atomicAdd(&cursor[d], 1);
    csr_src[pos] = s;
}

// batch is sorted: gstart[g] = lower_bound(batch, g); no atomics, no contention.
__global__ void gstart_kernel(const int* __restrict__ batch, int* __restrict__ gstart) {
    int g = threadIdx.x;
    if (g > NG) return;
    int lo = 0, hi = NN;
    while (lo < hi) {
        int mid = (lo + hi) >> 1;
        if (batch[mid] < g) lo = mid + 1; else hi = mid;
    }
    gstart[g] = lo;
}

// ---------------------------------------------------------------- dtype prep
__global__ void cvt_bf16_kernel(const float* __restrict__ in, short* __restrict__ out, int n4) {
    int i = blockIdx.x * blockDim.x + threadIdx.x;
    if (i >= n4) return;
    float4 v = ((const float4*)in)[i];
    short4 o;
    o.x = f2bf(v.x); o.y = f2bf(v.y); o.z = f2bf(v.z); o.w = f2bf(v.w);
    ((short4*)out)[i] = o;
}

// WT[n][k] = bf16(W[k][n]); 32x32 LDS tiles, coalesced both sides.
__global__ __launch_bounds__(256) void transpose_cvt_kernel(const float* __restrict__ W,
                                                            short* __restrict__ WT,
                                                            int K, int Nc) {
    __shared__ float tile[32][33];
    int bx = blockIdx.x * 32;   // n base
    int by = blockIdx.y * 32;   // k base
    int tx = threadIdx.x & 31, ty = threadIdx.x >> 5;
    for (int r = ty; r < 32; r += 8)
        tile[r][tx] = W[(size_t)(by + r) * Nc + bx + tx];
    __syncthreads();
    for (int r = ty; r < 32; r += 8)
        WT[(size_t)(bx + r) * K + by + tx] = f2bf(tile[tx][r]);
}

// ---------------------------------------------------------------- GEMM (bf16 MFMA, fp32 acc)
// C[M,Nc] = A[M,K] * B[K,Nc], A bf16 [M][K], BT bf16 [Nc][K].
// 64x64 tile, BK=64, 4 waves each owning a 32x32 quadrant (2x2 frags of 16x16x32).
// LDS XOR-swizzle (chunk ^= row&7, 16B chunks in 128B rows) -> 2-way (free) ds_read_b128.
#define GBM 64
#define GBN 64
#define GBK 64
__global__ __launch_bounds__(256) void gemm_bf16_kernel(const short* __restrict__ A,
                                                        const short* __restrict__ BT,
                                                        float* __restrict__ C,
                                                        int M, int K, int Nc) {
    __shared__ short Al[GBM * GBK];   // 8KB
    __shared__ short Bl[GBN * GBK];   // 8KB
    const int t = threadIdx.x;
    const int lane = t & 63, wid = t >> 6;
    const int wr = (wid >> 1) * 32, wc = (wid & 1) * 32;
    const int bm = blockIdx.x * GBM, bn = blockIdx.y * GBN;
    const int r0 = t >> 3, ch = t & 7;   // staging coords

    f32x4 acc[2][2] = {};

    for (int k0 = 0; k0 < K; k0 += GBK) {
#pragma unroll
        for (int p = 0; p < 2; p++) {
            int row = p * 32 + r0;
            int arow = bm + row; if (arow >= M) arow = M - 1;   // clamp: dup row, rows>=M never stored
            bfx8 av = *(const bfx8*)(A + (size_t)arow * K + k0 + ch * 8);
            bfx8 bv = *(const bfx8*)(BT + (size_t)(bn + row) * K + k0 + ch * 8);
            int wo = (row << 7) + (((ch ^ (row & 7))) << 4);
            *(bfx8*)((char*)Al + wo) = av;
            *(bfx8*)((char*)Bl + wo) = bv;
        }
        __syncthreads();
        bfx8 af[2][2], bfm[2][2];
#pragma unroll
        for (int m = 0; m < 2; m++)
#pragma unroll
            for (int kk = 0; kk < 2; kk++) {
                int rowa = wr + m * 16 + (lane & 15);
                int rowb = wc + m * 16 + (lane & 15);
                int c = kk * 4 + (lane >> 4);
                af[m][kk]  = *(const bfx8*)((const char*)Al + (rowa << 7) + (((c ^ (rowa & 7))) << 4));
                bfm[m][kk] = *(const bfx8*)((const char*)Bl + (rowb << 7) + (((c ^ (rowb & 7))) << 4));
            }
#pragma unroll
        for (int m = 0; m < 2; m++)
#pragma unroll
            for (int n = 0; n < 2; n++) {
                acc[m][n] = __builtin_amdgcn_mfma_f32_16x16x32_bf16(af[m][0], bfm[n][0], acc[m][n], 0, 0, 0);
                acc[m][n] = __builtin_amdgcn_mfma_f32_16x16x32_bf16(af[m][1], bfm[n][1], acc[m][n], 0, 0, 0);
            }
        __syncthreads();
    }
#pragma unroll
    for (int m = 0; m < 2; m++) {
        int row0 = bm + wr + m * 16 + ((lane >> 4) << 2);
#pragma unroll
        for (int n = 0; n < 2; n++) {
            int col = bn + wc + n * 16 + (lane & 15);
#pragma unroll
            for (int j = 0; j < 4; j++) {
                int row = row0 + j;
                if (row < M) C[(size_t)row * Nc + col] = acc[m][n][j];
            }
        }
    }
}

// ---------------------------------------------------------------- attention scores
__global__ void attn_score_kernel(const float* __restrict__ h,
                                  const float* __restrict__ asrc,
                                  const float* __restrict__ adst,
                                  float* __restrict__ es, float* __restrict__ ed,
                                  int F, int nheads) {
    int n = blockIdx.x;
    int t = threadIdx.x;
    float v = h[(size_t)n * F + t];
    float ps = v * asrc[t];
    float pd = v * adst[t];
    for (int s = 32; s > 0; s >>= 1) {
        ps += __shfl_down(ps, s);
        pd += __shfl_down(pd, s);
    }
    if ((t & 63) == 0) {
        int hd = t >> 6;
        es[n * nheads + hd] = ps;
        ed[n * nheads + hd] = pd;
    }
}

// ---------------------------------------------------------------- GAT agg + LN + relu + residual (heads=4, F=256)
__global__ __launch_bounds__(256) void gat_agg_ln_kernel(
    const float* __restrict__ h, const float* __restrict__ es, const float* __restrict__ ed,
    const int* __restrict__ off, const int* __restrict__ csr,
    const float* __restrict__ bias, const float* __restrict__ gamma, const float* __restrict__ beta,
    const float* __restrict__ resid, float* __restrict__ xout) {
    int n = blockIdx.x;
    int t = threadIdx.x;
    int head = t >> 6, lane = t & 63;
    int j0 = off[n], j1 = off[n + 1];
    float edn = ed[n * HEADS + head];

    float mloc = -INFINITY;
    for (int j = j0 + lane; j < j1; j += 64) {
        int s = csr[j];
        float e = es[s * HEADS + head] + edn;
        e = (e >= 0.f) ? e : SLOPE * e;
        mloc = fmaxf(mloc, e);
    }
    for (int s = 32; s > 0; s >>= 1) mloc = fmaxf(mloc, __shfl_xor(mloc, s));
    float ssum = 0.f;
    for (int j = j0 + lane; j < j1; j += 64) {
        int s = csr[j];
        float e = es[s * HEADS + head] + edn;
        e = (e >= 0.f) ? e : SLOPE * e;
        ssum += __expf(e - mloc);
    }
    for (int s = 32; s > 0; s >>= 1) ssum += __shfl_xor(ssum, s);

    float acc = 0.f;
    for (int j = j0; j < j1; j++) {
        int s = csr[j];
        float e = es[s * HEADS + head] + edn;
        e = (e >= 0.f) ? e : SLOPE * e;
        float w = __expf(e - mloc);
        acc += w * h[(size_t)s * 256 + t];
    }
    float v = acc / (ssum + 1e-16f) + bias[t];

    __shared__ float red[8];
    float ls = v, lq = v * v;
    for (int s = 32; s > 0; s >>= 1) { ls += __shfl_xor(ls, s); lq += __shfl_xor(lq, s); }
    if (lane == 0) { red[head] = ls; red[4 + head] = lq; }
    __syncthreads();
    float tot = red[0] + red[1] + red[2] + red[3];
    float totq = red[4] + red[5] + red[6] + red[7];
    float mu = tot * (1.0f / 256.0f);
    float var = totq * (1.0f / 256.0f) - mu * mu;
    float y = (v - mu) * rsqrtf(var + LN_EPS) * gamma[t] + beta[t];
    y = fmaxf(y, 0.f);
    xout[(size_t)n * 256 + t] = y + resid[(size_t)n * 256 + t];
}

// ---------------------------------------------------------------- final GAT (heads=1, F=64) + LN + relu
__global__ __launch_bounds__(64) void gat_final_kernel(
    const float* __restrict__ h, const float* __restrict__ es, const float* __restrict__ ed,
    const int* __restrict__ off, const int* __restrict__ csr,
    const float* __restrict__ bias, const float* __restrict__ gamma, const float* __restrict__ beta,
    float* __restrict__ xout) {
    int n = blockIdx.x;
    int t = threadIdx.x;
    int j0 = off[n], j1 = off[n + 1];
    float edn = ed[n];
    float mloc = -INFINITY;
    for (int j = j0 + t; j < j1; j += 64) {
        int s = csr[j];
        float e = es[s] + edn;
        e = (e >= 0.f) ? e : SLOPE * e;
        mloc = fmaxf(mloc, e);
    }
    for (int s = 32; s > 0; s >>= 1) mloc = fmaxf(mloc, __shfl_xor(mloc, s));
    float ssum = 0.f;
    for (int j = j0 + t; j < j1; j += 64) {
        int s = csr[j];
        float e = es[s] + edn;
        e = (e >= 0.f) ? e : SLOPE * e;
        ssum += __expf(e - mloc);
    }
    for (int s = 32; s > 0; s >>= 1) ssum += __shfl_xor(ssum, s);
    float acc = 0.f;
    for (int j = j0; j < j1; j++) {
        int s = csr[j];
        float e = es[s] + edn;
        e = (e >= 0.f) ? e : SLOPE * e;
        acc += __expf(e - mloc) * h[(size_t)s * 64 + t];
    }
    float v = acc / (ssum + 1e-16f) + bias[t];
    float ls = v, lq = v * v;
    for (int s = 32; s > 0; s >>= 1) { ls += __shfl_xor(ls, s); lq += __shfl_xor(lq, s); }
    float mu = ls * (1.0f / 64.0f);
    float var = lq * (1.0f / 64.0f) - mu * mu;
    float y = (v - mu) * rsqrtf(var + LN_EPS) * gamma[t] + beta[t];
    xout[(size_t)n * 64 + t] = fmaxf(y, 0.f);
}

// ---------------------------------------------------------------- pooling
__global__ __launch_bounds__(256) void pool_partial_kernel(
    const float* __restrict__ x, const int* __restrict__ gstart,
    float* __restrict__ gsum, unsigned* __restrict__ gmax) {
    int g = blockIdx.x, sp = blockIdx.y;
    int r0 = gstart[g], r1 = gstart[g + 1];
    int t = threadIdx.x, d = t & 63, rg = t >> 6;
    float sum = 0.f, mx = 0.f;
    for (int r = r0 + sp * 4 + rg; r < r1; r += 32) {
        float v = x[(size_t)r * 64 + d];
        sum += v;
        mx = fmaxf(mx, v);
    }
    __shared__ float S[256], M[256];
    S[t] = sum; M[t] = mx;
    __syncthreads();
    if (t < 64) {
        float s4 = S[t] + S[t + 64] + S[t + 128] + S[t + 192];
        float m4 = fmaxf(fmaxf(M[t], M[t + 64]), fmaxf(M[t + 128], M[t + 192]));
        atomicAdd(&gsum[g * 64 + t], s4);
        atomicMax(&gmax[g * 64 + t], __float_as_uint(m4));
    }
}

__global__ void pool_final_kernel(const float* __restrict__ gsum,
                                  const unsigned* __restrict__ gmax,
                                  const int* __restrict__ gstart,
                                  float* __restrict__ pout) {
    int g = blockIdx.x, d = threadIdx.x;
    float c = fmaxf((float)(gstart[g + 1] - gstart[g]), 1.0f);
    pout[g * 128 + d] = gsum[g * 64 + d] / c;
    pout[g * 128 + 64 + d] = __uint_as_float(gmax[g * 64 + d]);
}

// ---------------------------------------------------------------- launch
extern "C" void kernel_launch(void* const* d_in, const int* in_sizes, int n_in,
                              void* d_out, int out_size, void* d_ws, size_t ws_size,
                              hipStream_t stream) {
    const float* node_x = (const float*)d_in[0];
    const int*   ei     = (const int*)d_in[1];
    const int*   batch  = (const int*)d_in[2];
    const float* W1  = (const float*)d_in[3];
    const float* as1 = (const float*)d_in[4];
    const float* ad1 = (const float*)d_in[5];
    const float* b1  = (const float*)d_in[6];
    const float* g1  = (const float*)d_in[7];
    const float* be1 = (const float*)d_in[8];
    const float* W2  = (const float*)d_in[9];
    const float* as2 = (const float*)d_in[10];
    const float* ad2 = (const float*)d_in[11];
    const float* b2  = (const float*)d_in[12];
    const float* g2  = (const float*)d_in[13];
    const float* be2 = (const float*)d_in[14];
    const float* Wf  = (const float*)d_in[15];
    const float* asf = (const float*)d_in[16];
    const float* adf = (const float*)d_in[17];
    const float* bf  = (const float*)d_in[18];
    const float* gf  = (const float*)d_in[19];
    const float* bef = (const float*)d_in[20];
    float* out = (float*)d_out;

    char* w = (char*)d_ws;
    auto alloc = [&](size_t bytes) -> void* {
        void* p = (void*)w;
        w += (bytes + 255) & ~(size_t)255;
        return p;
    };
    float*    h      = (float*)alloc((size_t)NN * 256 * 4);
    float*    x1     = (float*)alloc((size_t)NN * 256 * 4);
    float*    x2     = (float*)alloc((size_t)NN * 256 * 4);
    short*    xb     = (short*)alloc((size_t)NN * 256 * 2);   // bf16 GEMM input
    short*    wt     = (short*)alloc((size_t)256 * 256 * 2);  // bf16 W^T (shared)
    float*    es     = (float*)alloc((size_t)NN * HEADS * 4);
    float*    ed     = (float*)alloc((size_t)NN * HEADS * 4);
    int*      counts = (int*)alloc((size_t)NN * 4);
    int*      off    = (int*)alloc((size_t)(NN + 1) * 4);
    int*      cursor = (int*)alloc((size_t)NN * 4);
    int*      csr    = (int*)alloc((size_t)TE * 4);
    int*      bsum   = (int*)alloc((size_t)128 * 4);
    int*      boff   = (int*)alloc((size_t)128 * 4);
    float*    gsum   = (float*)alloc((size_t)NG * 64 * 4);
    unsigned* gmax   = (unsigned*)alloc((size_t)NG * 64 * 4);
    int*      gstart = (int*)alloc((size_t)(NG + 1) * 4);

    hipMemsetAsync(counts, 0, (size_t)NN * 4, stream);
    hipMemsetAsync(gsum, 0, (size_t)NG * 64 * 4, stream);
    hipMemsetAsync(gmax, 0, (size_t)NG * 64 * 4, stream);

    const int NB = (NN + 255) / 256;   // 79

    // CSR build (no contended atomics)
    deg_kernel<<<(TE + 255) / 256, 256, 0, stream>>>(ei, counts);
    bsum_kernel<<<NB, 256, 0, stream>>>(counts, bsum);
    bscan_kernel<<<1, 128, 0, stream>>>(bsum, boff, NB);
    offsets_kernel<<<NB, 256, 0, stream>>>(counts, boff, off, cursor);
    csr_fill_kernel<<<(TE + 255) / 256, 256, 0, stream>>>(ei, cursor, csr);
    gstart_kernel<<<1, 32, 0, stream>>>(batch, gstart);

    const int n4 = NN * 256 / 4;
    dim3 tg256(256 / 32, 256 / 32);
    dim3 tg64(64 / 32, 256 / 32);
    dim3 gg256((NN + GBM - 1) / GBM, 256 / GBN);
    dim3 gg64((NN + GBM - 1) / GBM, 64 / GBN);

    // ---- layer 1
    cvt_bf16_kernel<<<(n4 + 255) / 256, 256, 0, stream>>>(node_x, xb, n4);
    transpose_cvt_kernel<<<tg256, 256, 0, stream>>>(W1, wt, 256, 256);
    gemm_bf16_kernel<<<gg256, 256, 0, stream>>>(xb, wt, h, NN, 256, 256);
    attn_score_kernel<<<NN, 256, 0, stream>>>(h, as1, ad1, es, ed, 256, HEADS);
    gat_agg_ln_kernel<<<NN, 256, 0, stream>>>(h, es, ed, off, csr, b1, g1, be1, node_x, x1);
    // ---- layer 2
    cvt_bf16_kernel<<<(n4 + 255) / 256, 256, 0, stream>>>(x1, xb, n4);
    transpose_cvt_kernel<<<tg256, 256, 0, stream>>>(W2, wt, 256, 256);
    gemm_bf16_kernel<<<gg256, 256, 0, stream>>>(xb, wt, h, NN, 256, 256);
    attn_score_kernel<<<NN, 256, 0, stream>>>(h, as2, ad2, es, ed, 256, HEADS);
    gat_agg_ln_kernel<<<NN, 256, 0, stream>>>(h, es, ed, off, csr, b2, g2, be2, x1, x2);
    // ---- final layer
    cvt_bf16_kernel<<<(n4 + 255) / 256, 256, 0, stream>>>(x2, xb, n4);
    transpose_cvt_kernel<<<tg64, 256, 0, stream>>>(Wf, wt, 256, 64);
    gemm_bf16_kernel<<<gg64, 256, 0, stream>>>(xb, wt, h, NN, 256, 64);
    attn_score_kernel<<<NN, 64, 0, stream>>>(h, asf, adf, es, ed, 64, 1);
    gat_final_kernel<<<NN, 64, 0, stream>>>(h, es, ed, off, csr, bf, gf, bef, out);
    // ---- pooling
    pool_partial_kernel<<<dim3(NG, 8), 256, 0, stream>>>(out, gstart, gsum, gmax);
    pool_final_kernel<<<NG, 64, 0, stream>>>(gsum, gmax, gstart, out + (size_t)NN * 64);
}

// Round 3
// 347.082 us; speedup vs baseline: 2.3520x; 1.3663x over previous
//
#include <hip/hip_runtime.h>
#include <cstdint>
#include <cstddef>

#define NN 20000
#define EE 320000
#define TE (EE + NN)      // edges + self loops
#define NG 16
#define HEADS 4
#define LN_EPS 1e-5f
#define SLOPE 0.2f

typedef __attribute__((ext_vector_type(8))) short bfx8;
typedef __attribute__((ext_vector_type(4))) float f32x4;

__device__ __forceinline__ short f2bf(float f) {
    unsigned u = __float_as_uint(f);
    u += 0x7FFFu + ((u >> 16) & 1u);   // RNE
    return (short)(u >> 16);
}
__device__ __forceinline__ float bf2f(unsigned short u) {
    return __uint_as_float(((unsigned)u) << 16);
}
__device__ __forceinline__ float lrelu(float e) {
    return (e >= 0.f) ? e : SLOPE * e;
}

// ---------------------------------------------------------------- CSR build
__global__ void deg_kernel(const int* __restrict__ ei, int* __restrict__ counts) {
    int i = blockIdx.x * blockDim.x + threadIdx.x;
    if (i >= TE) return;
    int d = (i < EE) ? ei[EE + i] : (i - EE);
    atomicAdd(&counts[d], 1);
}

__global__ __launch_bounds__(256) void bsum_kernel(const int* __restrict__ cnt,
                                                   int* __restrict__ bsum) {
    int b = blockIdx.x;
    int i = b * 256 + threadIdx.x;
    int v = (i < NN) ? cnt[i] : 0;
    for (int s = 32; s > 0; s >>= 1) v += __shfl_down(v, s);
    __shared__ int ws4[4];
    int lane = threadIdx.x & 63, w = threadIdx.x >> 6;
    if (lane == 0) ws4[w] = v;
    __syncthreads();
    if (threadIdx.x == 0) bsum[b] = ws4[0] + ws4[1] + ws4[2] + ws4[3];
}

__global__ void bscan_kernel(const int* __restrict__ bsum, int* __restrict__ boff, int nb) {
    __shared__ int s[128];
    int t = threadIdx.x;
    int v = (t < nb) ? bsum[t] : 0;
    s[t] = v;
    __syncthreads();
    for (int st = 1; st < 128; st <<= 1) {
        int a = (t >= st) ? s[t - st] : 0;
        __syncthreads();
        s[t] += a;
        __syncthreads();
    }
    if (t < nb) boff[t] = s[t] - v;   // exclusive
}

__global__ __launch_bounds__(256) void offsets_kernel(const int* __restrict__ cnt,
                                                      const int* __restrict__ boff,
                                                      int* __restrict__ off,
                                                      int* __restrict__ cursor) {
    int b = blockIdx.x, t = threadIdx.x;
    int i = b * 256 + t;
    int v = (i < NN) ? cnt[i] : 0;
    int lane = t & 63, w = t >> 6;
    int x = v;
    for (int s = 1; s < 64; s <<= 1) {
        int u = __shfl_up(x, s);
        if (lane >= s) x += u;
    }
    __shared__ int wsum[4];
    if (lane == 63) wsum[w] = x;
    __syncthreads();
    int pre = 0;
    for (int k = 0; k < w; k++) pre += wsum[k];
    int excl = (x + pre - v) + boff[b];
    if (i < NN) { cursor[i] = excl; off[i] = excl; }
    if (i == NN - 1) off[NN] = excl + v;
}

__global__ void csr_fill_kernel(const int* __restrict__ ei, int* __restrict__ cursor,
                                int* __restrict__ csr_src, int* __restrict__ csr_dst) {
    int i = blockIdx.x * blockDim.x + threadIdx.x;
    if (i >= TE) return;
    int s, d;
    if (i < EE) { s = ei[i]; d = ei[EE + i]; }
    else        { s = i - EE; d = s; }
    int pos = atomicAdd(&cursor[d], 1);
    csr_src[pos] = s;
    csr_dst[pos] = d;
}

// batch sorted -> binary search, no atomics
__global__ void gstart_kernel(const int* __restrict__ batch, int* __restrict__ gstart) {
    int g = threadIdx.x;
    if (g > NG) return;
    int lo = 0, hi = NN;
    while (lo < hi) {
        int mid = (lo + hi) >> 1;
        if (batch[mid] < g) lo = mid + 1; else hi = mid;
    }
    gstart[g] = lo;
}

// ---------------------------------------------------------------- dtype prep
__global__ void cvt_bf16_kernel(const float* __restrict__ in, unsigned short* __restrict__ out, int n4) {
    int i = blockIdx.x * blockDim.x + threadIdx.x;
    if (i >= n4) return;
    float4 v = ((const float4*)in)[i];
    ushort4 o;
    o.x = f2bf(v.x); o.y = f2bf(v.y); o.z = f2bf(v.z); o.w = f2bf(v.w);
    ((ushort4*)out)[i] = o;
}

__global__ __launch_bounds__(256) void transpose_cvt_kernel(const float* __restrict__ W,
                                                            short* __restrict__ WT,
                                                            int K, int Nc) {
    __shared__ float tile[32][33];
    int bx = blockIdx.x * 32;   // n base
    int by = blockIdx.y * 32;   // k base
    int tx = threadIdx.x & 31, ty = threadIdx.x >> 5;
    for (int r = ty; r < 32; r += 8)
        tile[r][tx] = W[(size_t)(by + r) * Nc + bx + tx];
    __syncthreads();
    for (int r = ty; r < 32; r += 8)
        WT[(size_t)(bx + r) * K + by + tx] = f2bf(tile[tx][r]);
}

// ---------------------------------------------------------------- GEMM (bf16 MFMA, fp32 acc)
#define GBM 64
#define GBN 64
#define GBK 64
__global__ __launch_bounds__(256) void gemm_bf16_kernel(const short* __restrict__ A,
                                                        const short* __restrict__ BT,
                                                        float* __restrict__ C,
                                                        unsigned short* __restrict__ Cb,
                                                        int M, int K, int Nc) {
    __shared__ short Al[GBM * GBK];
    __shared__ short Bl[GBN * GBK];
    const int t = threadIdx.x;
    const int lane = t & 63, wid = t >> 6;
    const int wr = (wid >> 1) * 32, wc = (wid & 1) * 32;
    const int bm = blockIdx.x * GBM, bn = blockIdx.y * GBN;
    const int r0 = t >> 3, ch = t & 7;

    f32x4 acc[2][2] = {};

    for (int k0 = 0; k0 < K; k0 += GBK) {
#pragma unroll
        for (int p = 0; p < 2; p++) {
            int row = p * 32 + r0;
            int arow = bm + row; if (arow >= M) arow = M - 1;
            bfx8 av = *(const bfx8*)(A + (size_t)arow * K + k0 + ch * 8);
            bfx8 bv = *(const bfx8*)(BT + (size_t)(bn + row) * K + k0 + ch * 8);
            int wo = (row << 7) + (((ch ^ (row & 7))) << 4);
            *(bfx8*)((char*)Al + wo) = av;
            *(bfx8*)((char*)Bl + wo) = bv;
        }
        __syncthreads();
        bfx8 af[2][2], bfm[2][2];
#pragma unroll
        for (int m = 0; m < 2; m++)
#pragma unroll
            for (int kk = 0; kk < 2; kk++) {
                int rowa = wr + m * 16 + (lane & 15);
                int rowb = wc + m * 16 + (lane & 15);
                int c = kk * 4 + (lane >> 4);
                af[m][kk]  = *(const bfx8*)((const char*)Al + (rowa << 7) + (((c ^ (rowa & 7))) << 4));
                bfm[m][kk] = *(const bfx8*)((const char*)Bl + (rowb << 7) + (((c ^ (rowb & 7))) << 4));
            }
#pragma unroll
        for (int m = 0; m < 2; m++)
#pragma unroll
            for (int n = 0; n < 2; n++) {
                acc[m][n] = __builtin_amdgcn_mfma_f32_16x16x32_bf16(af[m][0], bfm[n][0], acc[m][n], 0, 0, 0);
                acc[m][n] = __builtin_amdgcn_mfma_f32_16x16x32_bf16(af[m][1], bfm[n][1], acc[m][n], 0, 0, 0);
            }
        __syncthreads();
    }
#pragma unroll
    for (int m = 0; m < 2; m++) {
        int row0 = bm + wr + m * 16 + ((lane >> 4) << 2);
#pragma unroll
        for (int n = 0; n < 2; n++) {
            int col = bn + wc + n * 16 + (lane & 15);
#pragma unroll
            for (int j = 0; j < 4; j++) {
                int row = row0 + j;
                if (row < M) {
                    float v = acc[m][n][j];
                    C[(size_t)row * Nc + col] = v;
                    if (Cb) Cb[(size_t)row * Nc + col] = (unsigned short)f2bf(v);
                }
            }
        }
    }
}

// ---------------------------------------------------------------- attention scores
__global__ void attn_score_kernel(const float* __restrict__ h,
                                  const float* __restrict__ asrc,
                                  const float* __restrict__ adst,
                                  float* __restrict__ es, float* __restrict__ ed,
                                  int F, int nheads) {
    int n = blockIdx.x;
    int t = threadIdx.x;
    float v = h[(size_t)n * F + t];
    float ps = v * asrc[t];
    float pd = v * adst[t];
    for (int s = 32; s > 0; s >>= 1) {
        ps += __shfl_down(ps, s);
        pd += __shfl_down(pd, s);
    }
    if ((t & 63) == 0) {
        int hd = t >> 6;
        es[n * nheads + hd] = ps;
        ed[n * nheads + hd] = pd;
    }
}

// ---------------------------------------------------------------- edge weights (no max-subtraction; |e| <~ 16)
__global__ void wexp4_kernel(const int* __restrict__ csrs, const int* __restrict__ csrd,
                             const float* __restrict__ es, const float* __restrict__ ed,
                             float* __restrict__ wbuf) {
    int i = blockIdx.x * blockDim.x + threadIdx.x;
    if (i >= TE) return;
    int s = csrs[i], d = csrd[i];
    float4 a = ((const float4*)es)[s];
    float4 b = ((const float4*)ed)[d];
    float4 o;
    o.x = __expf(lrelu(a.x + b.x));
    o.y = __expf(lrelu(a.y + b.y));
    o.z = __expf(lrelu(a.z + b.z));
    o.w = __expf(lrelu(a.w + b.w));
    ((float4*)wbuf)[i] = o;
}

__global__ void wexp1_kernel(const int* __restrict__ csrs, const int* __restrict__ csrd,
                             const float* __restrict__ es, const float* __restrict__ ed,
                             float* __restrict__ wbuf) {
    int i = blockIdx.x * blockDim.x + threadIdx.x;
    if (i >= TE) return;
    wbuf[i] = __expf(lrelu(es[csrs[i]] + ed[csrd[i]]));
}

// ---------------------------------------------------------------- GAT agg + LN + relu + residual (heads=4, F=256)
// one wave per node; lane owns dims [4*lane, 4*lane+4); head = lane>>4
__global__ __launch_bounds__(256) void gat_agg_ln_kernel(
    const unsigned short* __restrict__ hb, const float* __restrict__ wbuf,
    const int* __restrict__ off, const int* __restrict__ csrs,
    const float* __restrict__ bias, const float* __restrict__ gamma, const float* __restrict__ beta,
    const float* __restrict__ resid, float* __restrict__ xout, unsigned short* __restrict__ xbout) {
    int wid = threadIdx.x >> 6, lane = threadIdx.x & 63;
    int n = blockIdx.x * 4 + wid;
    int hd = lane >> 4;
    int j0 = off[n], j1 = off[n + 1];

    // per-head sum of weights: 16 lanes of this head stride the edges
    float ssum = 0.f;
    for (int j = j0 + (lane & 15); j < j1; j += 16)
        ssum += wbuf[j * 4 + hd];
    ssum += __shfl_xor(ssum, 1);
    ssum += __shfl_xor(ssum, 2);
    ssum += __shfl_xor(ssum, 4);
    ssum += __shfl_xor(ssum, 8);

    // weighted accumulate (bf16 gather, 8B/lane/edge)
    float a0 = 0.f, a1 = 0.f, a2 = 0.f, a3 = 0.f;
    int d0 = lane * 4;
#pragma unroll 2
    for (int j = j0; j < j1; ++j) {
        int s = csrs[j];
        float wt = wbuf[j * 4 + hd];
        ushort4 u = *(const ushort4*)(hb + (size_t)s * 256 + d0);
        a0 += wt * bf2f(u.x);
        a1 += wt * bf2f(u.y);
        a2 += wt * bf2f(u.z);
        a3 += wt * bf2f(u.w);
    }
    float inv = 1.f / (ssum + 1e-16f);
    float4 bi = ((const float4*)bias)[lane];
    float v0 = a0 * inv + bi.x;
    float v1 = a1 * inv + bi.y;
    float v2 = a2 * inv + bi.z;
    float v3 = a3 * inv + bi.w;

    // LayerNorm over 256 dims (full-wave reduce)
    float ls = v0 + v1 + v2 + v3;
    float lq = v0 * v0 + v1 * v1 + v2 * v2 + v3 * v3;
    for (int s = 1; s < 64; s <<= 1) { ls += __shfl_xor(ls, s); lq += __shfl_xor(lq, s); }
    float mu = ls * (1.0f / 256.0f);
    float var = lq * (1.0f / 256.0f) - mu * mu;
    float rstd = rsqrtf(var + LN_EPS);
    float4 ga = ((const float4*)gamma)[lane];
    float4 be = ((const float4*)beta)[lane];
    float4 rs = ((const float4*)resid)[(size_t)n * 64 + lane];
    float y0 = fmaxf((v0 - mu) * rstd * ga.x + be.x, 0.f) + rs.x;
    float y1 = fmaxf((v1 - mu) * rstd * ga.y + be.y, 0.f) + rs.y;
    float y2 = fmaxf((v2 - mu) * rstd * ga.z + be.z, 0.f) + rs.z;
    float y3 = fmaxf((v3 - mu) * rstd * ga.w + be.w, 0.f) + rs.w;
    if (xout) {
        float4 o; o.x = y0; o.y = y1; o.z = y2; o.w = y3;
        ((float4*)xout)[(size_t)n * 64 + lane] = o;
    }
    ushort4 ob;
    ob.x = f2bf(y0); ob.y = f2bf(y1); ob.z = f2bf(y2); ob.w = f2bf(y3);
    ((ushort4*)xbout)[(size_t)n * 64 + lane] = ob;
}

// ---------------------------------------------------------------- final GAT (heads=1, F=64) + LN + relu
// one wave per node; lane owns dim lane
__global__ __launch_bounds__(256) void gat_final_kernel(
    const unsigned short* __restrict__ hb, const float* __restrict__ wf,
    const int* __restrict__ off, const int* __restrict__ csrs,
    const float* __restrict__ bias, const float* __restrict__ gamma, const float* __restrict__ beta,
    float* __restrict__ xout) {
    int wid = threadIdx.x >> 6, lane = threadIdx.x & 63;
    int n = blockIdx.x * 4 + wid;
    int j0 = off[n], j1 = off[n + 1];
    float ssum = 0.f;
    for (int j = j0 + lane; j < j1; j += 64) ssum += wf[j];
    for (int s = 1; s < 64; s <<= 1) ssum += __shfl_xor(ssum, s);
    float acc = 0.f;
#pragma unroll 2
    for (int j = j0; j < j1; ++j) {
        int s = csrs[j];
        acc += wf[j] * bf2f(hb[(size_t)s * 64 + lane]);
    }
    float v = acc / (ssum + 1e-16f) + bias[lane];
    float ls = v, lq = v * v;
    for (int s = 1; s < 64; s <<= 1) { ls += __shfl_xor(ls, s); lq += __shfl_xor(lq, s); }
    float mu = ls * (1.0f / 64.0f);
    float var = lq * (1.0f / 64.0f) - mu * mu;
    float y = (v - mu) * rsqrtf(var + LN_EPS) * gamma[lane] + beta[lane];
    xout[(size_t)n * 64 + lane] = fmaxf(y, 0.f);
}

// ---------------------------------------------------------------- pooling
__global__ __launch_bounds__(256) void pool_partial_kernel(
    const float* __restrict__ x, const int* __restrict__ gstart,
    float* __restrict__ gsum, unsigned* __restrict__ gmax) {
    int g = blockIdx.x, sp = blockIdx.y;
    int r0 = gstart[g], r1 = gstart[g + 1];
    int t = threadIdx.x, d = t & 63, rg = t >> 6;
    float sum = 0.f, mx = 0.f;
    for (int r = r0 + sp * 4 + rg; r < r1; r += 32) {
        float v = x[(size_t)r * 64 + d];
        sum += v;
        mx = fmaxf(mx, v);
    }
    __shared__ float S[256], M[256];
    S[t] = sum; M[t] = mx;
    __syncthreads();
    if (t < 64) {
        float s4 = S[t] + S[t + 64] + S[t + 128] + S[t + 192];
        float m4 = fmaxf(fmaxf(M[t], M[t + 64]), fmaxf(M[t + 128], M[t + 192]));
        atomicAdd(&gsum[g * 64 + t], s4);
        atomicMax(&gmax[g * 64 + t], __float_as_uint(m4));
    }
}

__global__ void pool_final_kernel(const float* __restrict__ gsum,
                                  const unsigned* __restrict__ gmax,
                                  const int* __restrict__ gstart,
                                  float* __restrict__ pout) {
    int g = blockIdx.x, d = threadIdx.x;
    float c = fmaxf((float)(gstart[g + 1] - gstart[g]), 1.0f);
    pout[g * 128 + d] = gsum[g * 64 + d] / c;
    pout[g * 128 + 64 + d] = __uint_as_float(gmax[g * 64 + d]);
}

// ---------------------------------------------------------------- launch
extern "C" void kernel_launch(void* const* d_in, const int* in_sizes, int n_in,
                              void* d_out, int out_size, void* d_ws, size_t ws_size,
                              hipStream_t stream) {
    const float* node_x = (const float*)d_in[0];
    const int*   ei     = (const int*)d_in[1];
    const int*   batch  = (const int*)d_in[2];
    const float* W1  = (const float*)d_in[3];
    const float* as1 = (const float*)d_in[4];
    const float* ad1 = (const float*)d_in[5];
    const float* b1  = (const float*)d_in[6];
    const float* g1  = (const float*)d_in[7];
    const float* be1 = (const float*)d_in[8];
    const float* W2  = (const float*)d_in[9];
    const float* as2 = (const float*)d_in[10];
    const float* ad2 = (const float*)d_in[11];
    const float* b2  = (const float*)d_in[12];
    const float* g2  = (const float*)d_in[13];
    const float* be2 = (const float*)d_in[14];
    const float* Wf  = (const float*)d_in[15];
    const float* asf = (const float*)d_in[16];
    const float* adf = (const float*)d_in[17];
    const float* bf  = (const float*)d_in[18];
    const float* gf  = (const float*)d_in[19];
    const float* bef = (const float*)d_in[20];
    float* out = (float*)d_out;

    char* w = (char*)d_ws;
    auto alloc = [&](size_t bytes) -> void* {
        void* p = (void*)w;
        w += (bytes + 255) & ~(size_t)255;
        return p;
    };
    float*          h    = (float*)alloc((size_t)NN * 256 * 4);
    unsigned short* hb   = (unsigned short*)alloc((size_t)NN * 256 * 2);
    float*          x1   = (float*)alloc((size_t)NN * 256 * 4);
    unsigned short* xb   = (unsigned short*)alloc((size_t)NN * 256 * 2);  // shared GEMM input (bf16)
    short*          wt   = (short*)alloc((size_t)256 * 256 * 2);
    float*          es   = (float*)alloc((size_t)NN * HEADS * 4);
    float*          ed   = (float*)alloc((size_t)NN * HEADS * 4);
    float*          wbuf = (float*)alloc((size_t)TE * HEADS * 4);         // edge weights (reused by final as scalar)
    int*      counts = (int*)alloc((size_t)NN * 4);
    int*      off    = (int*)alloc((size_t)(NN + 1) * 4);
    int*      cursor = (int*)alloc((size_t)NN * 4);
    int*      csrs   = (int*)alloc((size_t)TE * 4);
    int*      csrd   = (int*)alloc((size_t)TE * 4);
    int*      bsum   = (int*)alloc((size_t)128 * 4);
    int*      boff   = (int*)alloc((size_t)128 * 4);
    float*    gsum   = (float*)alloc((size_t)NG * 64 * 4);
    unsigned* gmax   = (unsigned*)alloc((size_t)NG * 64 * 4);
    int*      gstart = (int*)alloc((size_t)(NG + 1) * 4);

    hipMemsetAsync(counts, 0, (size_t)NN * 4, stream);
    hipMemsetAsync(gsum, 0, (size_t)NG * 64 * 4, stream);
    hipMemsetAsync(gmax, 0, (size_t)NG * 64 * 4, stream);

    const int NB = (NN + 255) / 256;   // 79
    const int EB = (TE + 255) / 256;

    // CSR build
    deg_kernel<<<EB, 256, 0, stream>>>(ei, counts);
    bsum_kernel<<<NB, 256, 0, stream>>>(counts, bsum);
    bscan_kernel<<<1, 128, 0, stream>>>(bsum, boff, NB);
    offsets_kernel<<<NB, 256, 0, stream>>>(counts, boff, off, cursor);
    csr_fill_kernel<<<EB, 256, 0, stream>>>(ei, cursor, csrs, csrd);
    gstart_kernel<<<1, 32, 0, stream>>>(batch, gstart);

    const int n4 = NN * 256 / 4;
    dim3 tg256(8, 8), tg64(2, 8);
    dim3 gg256((NN + GBM - 1) / GBM, 256 / GBN);
    dim3 gg64((NN + GBM - 1) / GBM, 1);

    // ---- layer 1
    cvt_bf16_kernel<<<(n4 + 255) / 256, 256, 0, stream>>>(node_x, xb, n4);
    transpose_cvt_kernel<<<tg256, 256, 0, stream>>>(W1, wt, 256, 256);
    gemm_bf16_kernel<<<gg256, 256, 0, stream>>>((const short*)xb, wt, h, hb, NN, 256, 256);
    attn_score_kernel<<<NN, 256, 0, stream>>>(h, as1, ad1, es, ed, 256, HEADS);
    wexp4_kernel<<<EB, 256, 0, stream>>>(csrs, csrd, es, ed, wbuf);
    gat_agg_ln_kernel<<<NN / 4, 256, 0, stream>>>(hb, wbuf, off, csrs, b1, g1, be1, node_x, x1, xb);
    // ---- layer 2
    transpose_cvt_kernel<<<tg256, 256, 0, stream>>>(W2, wt, 256, 256);
    gemm_bf16_kernel<<<gg256, 256, 0, stream>>>((const short*)xb, wt, h, hb, NN, 256, 256);
    attn_score_kernel<<<NN, 256, 0, stream>>>(h, as2, ad2, es, ed, 256, HEADS);
    wexp4_kernel<<<EB, 256, 0, stream>>>(csrs, csrd, es, ed, wbuf);
    gat_agg_ln_kernel<<<NN / 4, 256, 0, stream>>>(hb, wbuf, off, csrs, b2, g2, be2, x1, nullptr, xb);
    // ---- final layer
    transpose_cvt_kernel<<<tg64, 256, 0, stream>>>(Wf, wt, 256, 64);
    gemm_bf16_kernel<<<gg64, 256, 0, stream>>>((const short*)xb, wt, h, hb, NN, 256, 64);
    attn_score_kernel<<<NN, 64, 0, stream>>>(h, asf, adf, es, ed, 64, 1);
    wexp1_kernel<<<EB, 256, 0, stream>>>(csrs, csrd, es, ed, wbuf);
    gat_final_kernel<<<NN / 4, 256, 0, stream>>>(hb, wbuf, off, csrs, bf, gf, bef, out);
    // ---- pooling
    pool_partial_kernel<<<dim3(NG, 8), 256, 0, stream>>>(out, gstart, gsum, gmax);
    pool_final_kernel<<<NG, 64, 0, stream>>>(gsum, gmax, gstart, out + (size_t)NN * 64);
}

// Round 6
// 302.516 us; speedup vs baseline: 2.6985x; 1.1473x over previous
//
#include <hip/hip_runtime.h>
#include <cstdint>
#include <cstddef>

#define NN 20000
#define EE 320000
#define TE (EE + NN)      // edges + self loops
#define NG 16
#define HEADS 4
#define LN_EPS 1e-5f
#define SLOPE 0.2f

typedef __attribute__((ext_vector_type(8))) short bfx8;
typedef __attribute__((ext_vector_type(8))) unsigned short u16x8;
typedef __attribute__((ext_vector_type(4))) float f32x4;
typedef __attribute__((ext_vector_type(8))) float f32x8;

__device__ __forceinline__ short f2bf(float f) {
    unsigned u = __float_as_uint(f);
    u += 0x7FFFu + ((u >> 16) & 1u);   // RNE
    return (short)(u >> 16);
}
__device__ __forceinline__ float bf2f(unsigned short u) {
    return __uint_as_float(((unsigned)u) << 16);
}
__device__ __forceinline__ float lrelu(float e) {
    return (e >= 0.f) ? e : SLOPE * e;
}

// ---------------------------------------------------------------- CSR build
__global__ void deg_kernel(const int* __restrict__ ei, int* __restrict__ counts) {
    int i = blockIdx.x * blockDim.x + threadIdx.x;
    if (i >= TE) return;
    int d = (i < EE) ? ei[EE + i] : (i - EE);
    atomicAdd(&counts[d], 1);
}

__global__ __launch_bounds__(256) void bsum_kernel(const int* __restrict__ cnt,
                                                   int* __restrict__ bsum) {
    int b = blockIdx.x;
    int i = b * 256 + threadIdx.x;
    int v = (i < NN) ? cnt[i] : 0;
    for (int s = 32; s > 0; s >>= 1) v += __shfl_down(v, s);
    __shared__ int ws4[4];
    int lane = threadIdx.x & 63, w = threadIdx.x >> 6;
    if (lane == 0) ws4[w] = v;
    __syncthreads();
    if (threadIdx.x == 0) bsum[b] = ws4[0] + ws4[1] + ws4[2] + ws4[3];
}

__global__ void bscan_kernel(const int* __restrict__ bsum, int* __restrict__ boff, int nb) {
    __shared__ int s[128];
    int t = threadIdx.x;
    int v = (t < nb) ? bsum[t] : 0;
    s[t] = v;
    __syncthreads();
    for (int st = 1; st < 128; st <<= 1) {
        int a = (t >= st) ? s[t - st] : 0;
        __syncthreads();
        s[t] += a;
        __syncthreads();
    }
    if (t < nb) boff[t] = s[t] - v;   // exclusive
}

__global__ __launch_bounds__(256) void offsets_kernel(const int* __restrict__ cnt,
                                                      const int* __restrict__ boff,
                                                      int* __restrict__ off,
                                                      int* __restrict__ cursor) {
    int b = blockIdx.x, t = threadIdx.x;
    int i = b * 256 + t;
    int v = (i < NN) ? cnt[i] : 0;
    int lane = t & 63, w = t >> 6;
    int x = v;
    for (int s = 1; s < 64; s <<= 1) {
        int u = __shfl_up(x, s);
        if (lane >= s) x += u;
    }
    __shared__ int wsum[4];
    if (lane == 63) wsum[w] = x;
    __syncthreads();
    int pre = 0;
    for (int k = 0; k < w; k++) pre += wsum[k];
    int excl = (x + pre - v) + boff[b];
    if (i < NN) { cursor[i] = excl; off[i] = excl; }
    if (i == NN - 1) off[NN] = excl + v;
}

__global__ void csr_fill_kernel(const int* __restrict__ ei, int* __restrict__ cursor,
                                int* __restrict__ csr_src, int* __restrict__ csr_dst) {
    int i = blockIdx.x * blockDim.x + threadIdx.x;
    if (i >= TE) return;
    int s, d;
    if (i < EE) { s = ei[i]; d = ei[EE + i]; }
    else        { s = i - EE; d = s; }
    int pos = atomicAdd(&cursor[d], 1);
    csr_src[pos] = s;
    csr_dst[pos] = d;
}

// batch sorted -> binary search, no atomics
__global__ void gstart_kernel(const int* __restrict__ batch, int* __restrict__ gstart) {
    int g = threadIdx.x;
    if (g > NG) return;
    int lo = 0, hi = NN;
    while (lo < hi) {
        int mid = (lo + hi) >> 1;
        if (batch[mid] < g) lo = mid + 1; else hi = mid;
    }
    gstart[g] = lo;
}

// ---------------------------------------------------------------- dtype prep
__global__ void cvt_bf16_kernel(const float* __restrict__ in, unsigned short* __restrict__ out, int n4) {
    int i = blockIdx.x * blockDim.x + threadIdx.x;
    if (i >= n4) return;
    float4 v = ((const float4*)in)[i];
    ushort4 o;
    o.x = f2bf(v.x); o.y = f2bf(v.y); o.z = f2bf(v.z); o.w = f2bf(v.w);
    ((ushort4*)out)[i] = o;
}

__global__ __launch_bounds__(256) void transpose_cvt_kernel(const float* __restrict__ W,
                                                            short* __restrict__ WT,
                                                            int K, int Nc) {
    __shared__ float tile[32][33];
    int bx = blockIdx.x * 32;   // n base
    int by = blockIdx.y * 32;   // k base
    int tx = threadIdx.x & 31, ty = threadIdx.x >> 5;
    for (int r = ty; r < 32; r += 8)
        tile[r][tx] = W[(size_t)(by + r) * Nc + bx + tx];
    __syncthreads();
    for (int r = ty; r < 32; r += 8)
        WT[(size_t)(bx + r) * K + by + tx] = f2bf(tile[tx][r]);
}

// ---------------------------------------------------------------- GEMM (bf16 MFMA) + fused attention scores
// C = A*B^T-layout, writes bf16 Cb and per-(row,head) es/ed (GBN==64==head width ->
// each block holds a full head segment; plain stores, no atomics).
#define GBM 64
#define GBN 64
#define GBK 64
__global__ __launch_bounds__(256) void gemm_attn_kernel(const short* __restrict__ A,
                                                        const short* __restrict__ BT,
                                                        unsigned short* __restrict__ Cb,
                                                        float* __restrict__ es,
                                                        float* __restrict__ ed,
                                                        const float* __restrict__ av_src,
                                                        const float* __restrict__ av_dst,
                                                        int M, int K, int Nc, int nheads) {
    __shared__ short Al[GBM * GBK];
    __shared__ short Bl[GBN * GBK];
    __shared__ float sps[64][2];
    __shared__ float spd[64][2];
    const int t = threadIdx.x;
    const int lane = t & 63, wid = t >> 6;
    const int wr = (wid >> 1) * 32, wc = (wid & 1) * 32;
    const int bm = blockIdx.x * GBM, bn = blockIdx.y * GBN;
    const int r0 = t >> 3, ch = t & 7;

    f32x4 acc[2][2] = {};

    for (int k0 = 0; k0 < K; k0 += GBK) {
#pragma unroll
        for (int p = 0; p < 2; p++) {
            int row = p * 32 + r0;
            int arow = bm + row; if (arow >= M) arow = M - 1;
            bfx8 av = *(const bfx8*)(A + (size_t)arow * K + k0 + ch * 8);
            bfx8 bv = *(const bfx8*)(BT + (size_t)(bn + row) * K + k0 + ch * 8);
            int wo = (row << 7) + (((ch ^ (row & 7))) << 4);
            *(bfx8*)((char*)Al + wo) = av;
            *(bfx8*)((char*)Bl + wo) = bv;
        }
        __syncthreads();
        bfx8 af[2][2], bfm[2][2];
#pragma unroll
        for (int m = 0; m < 2; m++)
#pragma unroll
            for (int kk = 0; kk < 2; kk++) {
                int rowa = wr + m * 16 + (lane & 15);
                int rowb = wc + m * 16 + (lane & 15);
                int c = kk * 4 + (lane >> 4);
                af[m][kk]  = *(const bfx8*)((const char*)Al + (rowa << 7) + (((c ^ (rowa & 7))) << 4));
                bfm[m][kk] = *(const bfx8*)((const char*)Bl + (rowb << 7) + (((c ^ (rowb & 7))) << 4));
            }
#pragma unroll
        for (int m = 0; m < 2; m++)
#pragma unroll
            for (int n = 0; n < 2; n++) {
                acc[m][n] = __builtin_amdgcn_mfma_f32_16x16x32_bf16(af[m][0], bfm[n][0], acc[m][n], 0, 0, 0);
                acc[m][n] = __builtin_amdgcn_mfma_f32_16x16x32_bf16(af[m][1], bfm[n][1], acc[m][n], 0, 0, 0);
            }
        __syncthreads();
    }

    // ---- store bf16 output
#pragma unroll
    for (int m = 0; m < 2; m++) {
        int row0 = bm + wr + m * 16 + ((lane >> 4) << 2);
#pragma unroll
        for (int n = 0; n < 2; n++) {
            int col = bn + wc + n * 16 + (lane & 15);
#pragma unroll
            for (int j = 0; j < 4; j++) {
                int row = row0 + j;
                if (row < M) Cb[(size_t)row * Nc + col] = (unsigned short)f2bf(acc[m][n][j]);
            }
        }
    }

    // ---- fused attention scores: es/ed[row, head]
    const int hd = bn >> 6;
    float asv[2], adv[2];
#pragma unroll
    for (int n = 0; n < 2; n++) {
        int c = wc + n * 16 + (lane & 15);   // dim within head (0..63)
        asv[n] = av_src[hd * 64 + c];
        adv[n] = av_dst[hd * 64 + c];
    }
#pragma unroll
    for (int m = 0; m < 2; m++) {
#pragma unroll
        for (int j = 0; j < 4; j++) {
            float ps = acc[m][0][j] * asv[0] + acc[m][1][j] * asv[1];
            float pd = acc[m][0][j] * adv[0] + acc[m][1][j] * adv[1];
            ps += __shfl_xor(ps, 1); pd += __shfl_xor(pd, 1);
            ps += __shfl_xor(ps, 2); pd += __shfl_xor(pd, 2);
            ps += __shfl_xor(ps, 4); pd += __shfl_xor(pd, 4);
            ps += __shfl_xor(ps, 8); pd += __shfl_xor(pd, 8);
            if ((lane & 15) == 0) {
                int rl = wr + m * 16 + ((lane >> 4) << 2) + j;
                sps[rl][wid & 1] = ps;
                spd[rl][wid & 1] = pd;
            }
        }
    }
    __syncthreads();
    if (t < 64) {
        int row = bm + t;
        if (row < M) {
            es[(size_t)row * nheads + hd] = sps[t][0] + sps[t][1];
            ed[(size_t)row * nheads + hd] = spd[t][0] + spd[t][1];
        }
    }
}

// ---------------------------------------------------------------- edge weights
__global__ void wexp4_kernel(const int* __restrict__ csrs, const int* __restrict__ csrd,
                             const float* __restrict__ es, const float* __restrict__ ed,
                             float* __restrict__ wbuf) {
    int i = blockIdx.x * blockDim.x + threadIdx.x;
    if (i >= TE) return;
    int s = csrs[i], d = csrd[i];
    float4 a = ((const float4*)es)[s];
    float4 b = ((const float4*)ed)[d];
    float4 o;
    o.x = __expf(lrelu(a.x + b.x));
    o.y = __expf(lrelu(a.y + b.y));
    o.z = __expf(lrelu(a.z + b.z));
    o.w = __expf(lrelu(a.w + b.w));
    ((float4*)wbuf)[i] = o;
}

__global__ void wexp1_kernel(const int* __restrict__ csrs, const int* __restrict__ csrd,
                             const float* __restrict__ es, const float* __restrict__ ed,
                             float* __restrict__ wbuf) {
    int i = blockIdx.x * blockDim.x + threadIdx.x;
    if (i >= TE) return;
    wbuf[i] = __expf(lrelu(es[csrs[i]] + ed[csrd[i]]));
}

// ---------------------------------------------------------------- GAT agg + LN + relu + residual (heads=4, F=256)
// wave per node; 2 edges/iter (half = lane>>5), lane covers 8 dims (ushort8, 16B),
// 4x manual unroll -> 4 outstanding 16B gathers/lane. ssum folded into gather loop.
__global__ __launch_bounds__(256) void gat_agg_ln_kernel(
    const unsigned short* __restrict__ hb, const float* __restrict__ wbuf,
    const int* __restrict__ off, const int* __restrict__ csrs,
    const float* __restrict__ bias, const float* __restrict__ gamma, const float* __restrict__ beta,
    const float* __restrict__ resid, float* __restrict__ xout, unsigned short* __restrict__ xbout) {
    const int wid = threadIdx.x >> 6, lane = threadIdx.x & 63;
    const int n = blockIdx.x * 4 + wid;
    const int half = lane >> 5, sl = lane & 31;
    const int hd = sl >> 3;            // 8 lanes per head per half
    const int d0 = sl * 8;             // dims d0..d0+7
    const int j0 = off[n], j1 = off[n + 1];

    float acc[8] = {};
    float wsum = 0.f;
    int j = j0 + half;
    for (; j + 6 < j1; j += 8) {       // 4 edges per half per iter
        int s0 = csrs[j], s1 = csrs[j + 2], s2 = csrs[j + 4], s3 = csrs[j + 6];
        float w0 = wbuf[j * 4 + hd];
        float w1 = wbuf[(j + 2) * 4 + hd];
        float w2 = wbuf[(j + 4) * 4 + hd];
        float w3 = wbuf[(j + 6) * 4 + hd];
        u16x8 r0 = *(const u16x8*)(hb + (size_t)s0 * 256 + d0);
        u16x8 r1 = *(const u16x8*)(hb + (size_t)s1 * 256 + d0);
        u16x8 r2 = *(const u16x8*)(hb + (size_t)s2 * 256 + d0);
        u16x8 r3 = *(const u16x8*)(hb + (size_t)s3 * 256 + d0);
        wsum += (w0 + w1) + (w2 + w3);
#pragma unroll
        for (int k = 0; k < 8; k++)
            acc[k] += w0 * bf2f(r0[k]) + w1 * bf2f(r1[k]) + w2 * bf2f(r2[k]) + w3 * bf2f(r3[k]);
    }
    for (; j < j1; j += 2) {
        int s = csrs[j];
        float wt = wbuf[j * 4 + hd];
        u16x8 r = *(const u16x8*)(hb + (size_t)s * 256 + d0);
        wsum += wt;
#pragma unroll
        for (int k = 0; k < 8; k++) acc[k] += wt * bf2f(r[k]);
    }
    // combine halves (each half has the full 256 dims across its 32 lanes)
    wsum += __shfl_xor(wsum, 32);
#pragma unroll
    for (int k = 0; k < 8; k++) acc[k] += __shfl_xor(acc[k], 32);

    float inv = 1.f / (wsum + 1e-16f);
    f32x8 bi = *(const f32x8*)(bias + d0);
    float v[8];
    float ls = 0.f, lq = 0.f;
#pragma unroll
    for (int k = 0; k < 8; k++) {
        v[k] = acc[k] * inv + bi[k];
        ls += v[k];
        lq += v[k] * v[k];
    }
    ls += __shfl_xor(ls, 1);  lq += __shfl_xor(lq, 1);
    ls += __shfl_xor(ls, 2);  lq += __shfl_xor(lq, 2);
    ls += __shfl_xor(ls, 4);  lq += __shfl_xor(lq, 4);
    ls += __shfl_xor(ls, 8);  lq += __shfl_xor(lq, 8);
    ls += __shfl_xor(ls, 16); lq += __shfl_xor(lq, 16);
    float mu = ls * (1.0f / 256.0f);
    float var = lq * (1.0f / 256.0f) - mu * mu;
    float rstd = rsqrtf(var + LN_EPS);
    f32x8 ga = *(const f32x8*)(gamma + d0);
    f32x8 be = *(const f32x8*)(beta + d0);
    // resid loaded by half 0 only; half 1 receives y via shfl
    f32x8 rs = {};
    if (half == 0) rs = *(const f32x8*)(resid + (size_t)n * 256 + d0);
    float y[8];
#pragma unroll
    for (int k = 0; k < 8; k++) {
        float yy = fmaxf((v[k] - mu) * rstd * ga[k] + be[k], 0.f) + rs[k];
        float tt = __shfl_xor(yy, 32);
        y[k] = half ? tt : yy;
    }
    if (half == 0) {
        if (xout) {
            f32x8 o;
#pragma unroll
            for (int k = 0; k < 8; k++) o[k] = y[k];
            *(f32x8*)(xout + (size_t)n * 256 + d0) = o;
        }
    } else {
        u16x8 ob;
#pragma unroll
        for (int k = 0; k < 8; k++) ob[k] = (unsigned short)f2bf(y[k]);
        *(u16x8*)(xbout + (size_t)n * 256 + d0) = ob;
    }
}

// ---------------------------------------------------------------- final GAT (heads=1, F=64) + LN + relu
// wave per node; 4 edges/iter (quarter = lane>>4), lane covers 4 dims (ushort4, 8B), 2x unroll.
__global__ __launch_bounds__(256) void gat_final_kernel(
    const unsigned short* __restrict__ hb, const float* __restrict__ wf,
    const int* __restrict__ off, const int* __restrict__ csrs,
    const float* __restrict__ bias, const float* __restrict__ gamma, const float* __restrict__ beta,
    float* __restrict__ xout) {
    const int wid = threadIdx.x >> 6, lane = threadIdx.x & 63;
    const int n = blockIdx.x * 4 + wid;
    const int q = lane >> 4, sq = lane & 15;
    const int d0 = sq * 4;
    const int j0 = off[n], j1 = off[n + 1];

    float acc[4] = {};
    float wsum = 0.f;
    int j = j0 + q;
    for (; j + 4 < j1; j += 8) {       // 2 edges per quarter per iter
        int s0 = csrs[j], s1 = csrs[j + 4];
        float w0 = wf[j], w1 = wf[j + 4];
        ushort4 r0 = *(const ushort4*)(hb + (size_t)s0 * 64 + d0);
        ushort4 r1 = *(const ushort4*)(hb + (size_t)s1 * 64 + d0);
        wsum += w0 + w1;
        acc[0] += w0 * bf2f(r0.x) + w1 * bf2f(r1.x);
        acc[1] += w0 * bf2f(r0.y) + w1 * bf2f(r1.y);
        acc[2] += w0 * bf2f(r0.z) + w1 * bf2f(r1.z);
        acc[3] += w0 * bf2f(r0.w) + w1 * bf2f(r1.w);
    }
    for (; j < j1; j += 4) {
        int s = csrs[j];
        float wt = wf[j];
        ushort4 r = *(const ushort4*)(hb + (size_t)s * 64 + d0);
        wsum += wt;
        acc[0] += wt * bf2f(r.x);
        acc[1] += wt * bf2f(r.y);
        acc[2] += wt * bf2f(r.z);
        acc[3] += wt * bf2f(r.w);
    }
    // combine quarters
    wsum += __shfl_xor(wsum, 16);
    wsum += __shfl_xor(wsum, 32);
#pragma unroll
    for (int k = 0; k < 4; k++) {
        acc[k] += __shfl_xor(acc[k], 16);
        acc[k] += __shfl_xor(acc[k], 32);
    }
    float inv = 1.f / (wsum + 1e-16f);
    float4 bi = *(const float4*)(bias + d0);
    float v[4];
    float ls = 0.f, lq = 0.f;
    v[0] = acc[0] * inv + bi.x; v[1] = acc[1] * inv + bi.y;
    v[2] = acc[2] * inv + bi.z; v[3] = acc[3] * inv + bi.w;
#pragma unroll
    for (int k = 0; k < 4; k++) { ls += v[k]; lq += v[k] * v[k]; }
    ls += __shfl_xor(ls, 1); lq += __shfl_xor(lq, 1);
    ls += __shfl_xor(ls, 2); lq += __shfl_xor(lq, 2);
    ls += __shfl_xor(ls, 4); lq += __shfl_xor(lq, 4);
    ls += __shfl_xor(ls, 8); lq += __shfl_xor(lq, 8);
    float mu = ls * (1.0f / 64.0f);
    float var = lq * (1.0f / 64.0f) - mu * mu;
    float rstd = rsqrtf(var + LN_EPS);
    if (q == 0) {
        float4 ga = *(const float4*)(gamma + d0);
        float4 be = *(const float4*)(beta + d0);
        float4 o;
        o.x = fmaxf((v[0] - mu) * rstd * ga.x + be.x, 0.f);
        o.y = fmaxf((v[1] - mu) * rstd * ga.y + be.y, 0.f);
        o.z = fmaxf((v[2] - mu) * rstd * ga.z + be.z, 0.f);
        o.w = fmaxf((v[3] - mu) * rstd * ga.w + be.w, 0.f);
        *(float4*)(xout + (size_t)n * 64 + d0) = o;
    }
}

// ---------------------------------------------------------------- pooling
__global__ __launch_bounds__(256) void pool_partial_kernel(
    const float* __restrict__ x, const int* __restrict__ gstart,
    float* __restrict__ gsum, unsigned* __restrict__ gmax) {
    int g = blockIdx.x, sp = blockIdx.y;
    int r0 = gstart[g], r1 = gstart[g + 1];
    int t = threadIdx.x, d = t & 63, rg = t >> 6;
    float sum = 0.f, mx = 0.f;
    for (int r = r0 + sp * 4 + rg; r < r1; r += 32) {
        float v = x[(size_t)r * 64 + d];
        sum += v;
        mx = fmaxf(mx, v);
    }
    __shared__ float S[256], M[256];
    S[t] = sum; M[t] = mx;
    __syncthreads();
    if (t < 64) {
        float s4 = S[t] + S[t + 64] + S[t + 128] + S[t + 192];
        float m4 = fmaxf(fmaxf(M[t], M[t + 64]), fmaxf(M[t + 128], M[t + 192]));
        atomicAdd(&gsum[g * 64 + t], s4);
        atomicMax(&gmax[g * 64 + t], __float_as_uint(m4));
    }
}

__global__ void pool_final_kernel(const float* __restrict__ gsum,
                                  const unsigned* __restrict__ gmax,
                                  const int* __restrict__ gstart,
                                  float* __restrict__ pout) {
    int g = blockIdx.x, d = threadIdx.x;
    float c = fmaxf((float)(gstart[g + 1] - gstart[g]), 1.0f);
    pout[g * 128 + d] = gsum[g * 64 + d] / c;
    pout[g * 128 + 64 + d] = __uint_as_float(gmax[g * 64 + d]);
}

// ---------------------------------------------------------------- launch
extern "C" void kernel_launch(void* const* d_in, const int* in_sizes, int n_in,
                              void* d_out, int out_size, void* d_ws, size_t ws_size,
                              hipStream_t stream) {
    const float* node_x = (const float*)d_in[0];
    const int*   ei     = (const int*)d_in[1];
    const int*   batch  = (const int*)d_in[2];
    const float* W1  = (const float*)d_in[3];
    const float* as1 = (const float*)d_in[4];
    const float* ad1 = (const float*)d_in[5];
    const float* b1  = (const float*)d_in[6];
    const float* g1  = (const float*)d_in[7];
    const float* be1 = (const float*)d_in[8];
    const float* W2  = (const float*)d_in[9];
    const float* as2 = (const float*)d_in[10];
    const float* ad2 = (const float*)d_in[11];
    const float* b2  = (const float*)d_in[12];
    const float* g2  = (const float*)d_in[13];
    const float* be2 = (const float*)d_in[14];
    const float* Wf  = (const float*)d_in[15];
    const float* asf = (const float*)d_in[16];
    const float* adf = (const float*)d_in[17];
    const float* bf  = (const float*)d_in[18];
    const float* gf  = (const float*)d_in[19];
    const float* bef = (const float*)d_in[20];
    float* out = (float*)d_out;

    char* w = (char*)d_ws;
    auto alloc = [&](size_t bytes) -> void* {
        void* p = (void*)w;
        w += (bytes + 255) & ~(size_t)255;
        return p;
    };
    unsigned short* hb   = (unsigned short*)alloc((size_t)NN * 256 * 2);  // GEMM bf16 out
    float*          x1   = (float*)alloc((size_t)NN * 256 * 4);           // layer-1 out (fp32 resid)
    unsigned short* xb   = (unsigned short*)alloc((size_t)NN * 256 * 2);  // GEMM bf16 in
    short*          wt   = (short*)alloc((size_t)256 * 256 * 2);
    float*          es   = (float*)alloc((size_t)NN * HEADS * 4);
    float*          ed   = (float*)alloc((size_t)NN * HEADS * 4);
    float*          wbuf = (float*)alloc((size_t)TE * HEADS * 4);
    int*      counts = (int*)alloc((size_t)NN * 4);
    int*      off    = (int*)alloc((size_t)(NN + 1) * 4);
    int*      cursor = (int*)alloc((size_t)NN * 4);
    int*      csrs   = (int*)alloc((size_t)TE * 4);
    int*      csrd   = (int*)alloc((size_t)TE * 4);
    int*      bsum   = (int*)alloc((size_t)128 * 4);
    int*      boff   = (int*)alloc((size_t)128 * 4);
    float*    gsum   = (float*)alloc((size_t)NG * 64 * 4);
    unsigned* gmax   = (unsigned*)alloc((size_t)NG * 64 * 4);
    int*      gstart = (int*)alloc((size_t)(NG + 1) * 4);

    hipMemsetAsync(counts, 0, (size_t)NN * 4, stream);
    hipMemsetAsync(gsum, 0, (size_t)NG * 64 * 4, stream);
    hipMemsetAsync(gmax, 0, (size_t)NG * 64 * 4, stream);

    const int NB = (NN + 255) / 256;   // 79
    const int EB = (TE + 255) / 256;

    // CSR build
    deg_kernel<<<EB, 256, 0, stream>>>(ei, counts);
    bsum_kernel<<<NB, 256, 0, stream>>>(counts, bsum);
    bscan_kernel<<<1, 128, 0, stream>>>(bsum, boff, NB);
    offsets_kernel<<<NB, 256, 0, stream>>>(counts, boff, off, cursor);
    csr_fill_kernel<<<EB, 256, 0, stream>>>(ei, cursor, csrs, csrd);
    gstart_kernel<<<1, 32, 0, stream>>>(batch, gstart);

    const int n4 = NN * 256 / 4;
    dim3 tg256(8, 8), tg64(2, 8);
    dim3 gg256((NN + GBM - 1) / GBM, 256 / GBN);
    dim3 gg64((NN + GBM - 1) / GBM, 1);

    // ---- layer 1
    cvt_bf16_kernel<<<(n4 + 255) / 256, 256, 0, stream>>>(node_x, xb, n4);
    transpose_cvt_kernel<<<tg256, 256, 0, stream>>>(W1, wt, 256, 256);
    gemm_attn_kernel<<<gg256, 256, 0, stream>>>((const short*)xb, wt, hb, es, ed, as1, ad1, NN, 256, 256, HEADS);
    wexp4_kernel<<<EB, 256, 0, stream>>>(csrs, csrd, es, ed, wbuf);
    gat_agg_ln_kernel<<<NN / 4, 256, 0, stream>>>(hb, wbuf, off, csrs, b1, g1, be1, node_x, x1, xb);
    // ---- layer 2
    transpose_cvt_kernel<<<tg256, 256, 0, stream>>>(W2, wt, 256, 256);
    gemm_attn_kernel<<<gg256, 256, 0, stream>>>((const short*)xb, wt, hb, es, ed, as2, ad2, NN, 256, 256, HEADS);
    wexp4_kernel<<<EB, 256, 0, stream>>>(csrs, csrd, es, ed, wbuf);
    gat_agg_ln_kernel<<<NN / 4, 256, 0, stream>>>(hb, wbuf, off, csrs, b2, g2, be2, x1, nullptr, xb);
    // ---- final layer
    transpose_cvt_kernel<<<tg64, 256, 0, stream>>>(Wf, wt, 256, 64);
    gemm_attn_kernel<<<gg64, 256, 0, stream>>>((const short*)xb, wt, hb, es, ed, asf, adf, NN, 256, 64, 1);
    wexp1_kernel<<<EB, 256, 0, stream>>>(csrs, csrd, es, ed, wbuf);
    gat_final_kernel<<<NN / 4, 256, 0, stream>>>(hb, wbuf, off, csrs, bf, gf, bef, out);
    // ---- pooling
    pool_partial_kernel<<<dim3(NG, 8), 256, 0, stream>>>(out, gstart, gsum, gmax);
    pool_final_kernel<<<NG, 64, 0, stream>>>(gsum, gmax, gstart, out + (size_t)NN * 64);
}

// Round 9
// 283.143 us; speedup vs baseline: 2.8832x; 1.0684x over previous
//
#include <hip/hip_runtime.h>
#include <cstdint>
#include <cstddef>

#define NN 20000
#define EE 320000
#define TE (EE + NN)      // edges + self loops
#define NG 16
#define HEADS 4
#define LN_EPS 1e-5f
#define SLOPE 0.2f

typedef __attribute__((ext_vector_type(8))) short bfx8;
typedef __attribute__((ext_vector_type(8))) unsigned short u16x8;
typedef __attribute__((ext_vector_type(4))) float f32x4;
typedef __attribute__((ext_vector_type(8))) float f32x8;

__device__ __forceinline__ short f2bf(float f) {
    unsigned u = __float_as_uint(f);
    u += 0x7FFFu + ((u >> 16) & 1u);   // RNE
    return (short)(u >> 16);
}
__device__ __forceinline__ float bf2f(unsigned short u) {
    return __uint_as_float(((unsigned)u) << 16);
}
__device__ __forceinline__ float lrelu(float e) {
    return (e >= 0.f) ? e : SLOPE * e;
}

// ---------------------------------------------------------------- CSR build
__global__ void deg_kernel(const int* __restrict__ ei, int* __restrict__ counts) {
    int i = blockIdx.x * blockDim.x + threadIdx.x;
    if (i >= TE) return;
    int d = (i < EE) ? ei[EE + i] : (i - EE);
    atomicAdd(&counts[d], 1);
}

__global__ __launch_bounds__(256) void bsum_kernel(const int* __restrict__ cnt,
                                                   int* __restrict__ bsum) {
    int b = blockIdx.x;
    int i = b * 256 + threadIdx.x;
    int v = (i < NN) ? cnt[i] : 0;
    for (int s = 32; s > 0; s >>= 1) v += __shfl_down(v, s);
    __shared__ int ws4[4];
    int lane = threadIdx.x & 63, w = threadIdx.x >> 6;
    if (lane == 0) ws4[w] = v;
    __syncthreads();
    if (threadIdx.x == 0) bsum[b] = ws4[0] + ws4[1] + ws4[2] + ws4[3];
}

__global__ void bscan_kernel(const int* __restrict__ bsum, int* __restrict__ boff, int nb) {
    __shared__ int s[128];
    int t = threadIdx.x;
    int v = (t < nb) ? bsum[t] : 0;
    s[t] = v;
    __syncthreads();
    for (int st = 1; st < 128; st <<= 1) {
        int a = (t >= st) ? s[t - st] : 0;
        __syncthreads();
        s[t] += a;
        __syncthreads();
    }
    if (t < nb) boff[t] = s[t] - v;   // exclusive
}

__global__ __launch_bounds__(256) void offsets_kernel(const int* __restrict__ cnt,
                                                      const int* __restrict__ boff,
                                                      int* __restrict__ off,
                                                      int* __restrict__ cursor) {
    int b = blockIdx.x, t = threadIdx.x;
    int i = b * 256 + t;
    int v = (i < NN) ? cnt[i] : 0;
    int lane = t & 63, w = t >> 6;
    int x = v;
    for (int s = 1; s < 64; s <<= 1) {
        int u = __shfl_up(x, s);
        if (lane >= s) x += u;
    }
    __shared__ int wsum[4];
    if (lane == 63) wsum[w] = x;
    __syncthreads();
    int pre = 0;
    for (int k = 0; k < w; k++) pre += wsum[k];
    int excl = (x + pre - v) + boff[b];
    if (i < NN) { cursor[i] = excl; off[i] = excl; }
    if (i == NN - 1) off[NN] = excl + v;
}

__global__ void csr_fill_kernel(const int* __restrict__ ei, int* __restrict__ cursor,
                                int* __restrict__ csr_src) {
    int i = blockIdx.x * blockDim.x + threadIdx.x;
    if (i >= TE) return;
    int s, d;
    if (i < EE) { s = ei[i]; d = ei[EE + i]; }
    else        { s = i - EE; d = s; }
    int pos = atomicAdd(&cursor[d], 1);
    csr_src[pos] = s;
}

// batch sorted -> binary search, no atomics
__global__ void gstart_kernel(const int* __restrict__ batch, int* __restrict__ gstart) {
    int g = threadIdx.x;
    if (g > NG) return;
    int lo = 0, hi = NN;
    while (lo < hi) {
        int mid = (lo + hi) >> 1;
        if (batch[mid] < g) lo = mid + 1; else hi = mid;
    }
    gstart[g] = lo;
}

// ---------------------------------------------------------------- dtype prep
__global__ void cvt_bf16_kernel(const float* __restrict__ in, unsigned short* __restrict__ out, int n4) {
    int i = blockIdx.x * blockDim.x + threadIdx.x;
    if (i >= n4) return;
    float4 v = ((const float4*)in)[i];
    ushort4 o;
    o.x = f2bf(v.x); o.y = f2bf(v.y); o.z = f2bf(v.z); o.w = f2bf(v.w);
    ((ushort4*)out)[i] = o;
}

__global__ __launch_bounds__(256) void transpose_cvt_kernel(const float* __restrict__ W,
                                                            short* __restrict__ WT,
                                                            int K, int Nc) {
    __shared__ float tile[32][33];
    int bx = blockIdx.x * 32;   // n base
    int by = blockIdx.y * 32;   // k base
    int tx = threadIdx.x & 31, ty = threadIdx.x >> 5;
    for (int r = ty; r < 32; r += 8)
        tile[r][tx] = W[(size_t)(by + r) * Nc + bx + tx];
    __syncthreads();
    for (int r = ty; r < 32; r += 8)
        WT[(size_t)(bx + r) * K + by + tx] = f2bf(tile[tx][r]);
}

// ---------------------------------------------------------------- GEMM (bf16 MFMA) + fused attention scores
#define GBM 64
#define GBN 64
#define GBK 64
__global__ __launch_bounds__(256) void gemm_attn_kernel(const short* __restrict__ A,
                                                        const short* __restrict__ BT,
                                                        unsigned short* __restrict__ Cb,
                                                        float* __restrict__ es,
                                                        float* __restrict__ ed,
                                                        const float* __restrict__ av_src,
                                                        const float* __restrict__ av_dst,
                                                        int M, int K, int Nc, int nheads) {
    __shared__ short Al[GBM * GBK];
    __shared__ short Bl[GBN * GBK];
    __shared__ float sps[64][2];
    __shared__ float spd[64][2];
    const int t = threadIdx.x;
    const int lane = t & 63, wid = t >> 6;
    const int wr = (wid >> 1) * 32, wc = (wid & 1) * 32;
    const int bm = blockIdx.x * GBM, bn = blockIdx.y * GBN;
    const int r0 = t >> 3, ch = t & 7;

    f32x4 acc[2][2] = {};

    for (int k0 = 0; k0 < K; k0 += GBK) {
#pragma unroll
        for (int p = 0; p < 2; p++) {
            int row = p * 32 + r0;
            int arow = bm + row; if (arow >= M) arow = M - 1;
            bfx8 av = *(const bfx8*)(A + (size_t)arow * K + k0 + ch * 8);
            bfx8 bv = *(const bfx8*)(BT + (size_t)(bn + row) * K + k0 + ch * 8);
            int wo = (row << 7) + (((ch ^ (row & 7))) << 4);
            *(bfx8*)((char*)Al + wo) = av;
            *(bfx8*)((char*)Bl + wo) = bv;
        }
        __syncthreads();
        bfx8 af[2][2], bfm[2][2];
#pragma unroll
        for (int m = 0; m < 2; m++)
#pragma unroll
            for (int kk = 0; kk < 2; kk++) {
                int rowa = wr + m * 16 + (lane & 15);
                int rowb = wc + m * 16 + (lane & 15);
                int c = kk * 4 + (lane >> 4);
                af[m][kk]  = *(const bfx8*)((const char*)Al + (rowa << 7) + (((c ^ (rowa & 7))) << 4));
                bfm[m][kk] = *(const bfx8*)((const char*)Bl + (rowb << 7) + (((c ^ (rowb & 7))) << 4));
            }
#pragma unroll
        for (int m = 0; m < 2; m++)
#pragma unroll
            for (int n = 0; n < 2; n++) {
                acc[m][n] = __builtin_amdgcn_mfma_f32_16x16x32_bf16(af[m][0], bfm[n][0], acc[m][n], 0, 0, 0);
                acc[m][n] = __builtin_amdgcn_mfma_f32_16x16x32_bf16(af[m][1], bfm[n][1], acc[m][n], 0, 0, 0);
            }
        __syncthreads();
    }

    // ---- store bf16 output
#pragma unroll
    for (int m = 0; m < 2; m++) {
        int row0 = bm + wr + m * 16 + ((lane >> 4) << 2);
#pragma unroll
        for (int n = 0; n < 2; n++) {
            int col = bn + wc + n * 16 + (lane & 15);
#pragma unroll
            for (int j = 0; j < 4; j++) {
                int row = row0 + j;
                if (row < M) Cb[(size_t)row * Nc + col] = (unsigned short)f2bf(acc[m][n][j]);
            }
        }
    }

    // ---- fused attention scores: es/ed[row, head]
    const int hd = bn >> 6;
    float asv[2], adv[2];
#pragma unroll
    for (int n = 0; n < 2; n++) {
        int c = wc + n * 16 + (lane & 15);   // dim within head (0..63)
        asv[n] = av_src[hd * 64 + c];
        adv[n] = av_dst[hd * 64 + c];
    }
#pragma unroll
    for (int m = 0; m < 2; m++) {
#pragma unroll
        for (int j = 0; j < 4; j++) {
            float ps = acc[m][0][j] * asv[0] + acc[m][1][j] * asv[1];
            float pd = acc[m][0][j] * adv[0] + acc[m][1][j] * adv[1];
            ps += __shfl_xor(ps, 1); pd += __shfl_xor(pd, 1);
            ps += __shfl_xor(ps, 2); pd += __shfl_xor(pd, 2);
            ps += __shfl_xor(ps, 4); pd += __shfl_xor(pd, 4);
            ps += __shfl_xor(ps, 8); pd += __shfl_xor(pd, 8);
            if ((lane & 15) == 0) {
                int rl = wr + m * 16 + ((lane >> 4) << 2) + j;
                sps[rl][wid & 1] = ps;
                spd[rl][wid & 1] = pd;
            }
        }
    }
    __syncthreads();
    if (t < 64) {
        int row = bm + t;
        if (row < M) {
            es[(size_t)row * nheads + hd] = sps[t][0] + sps[t][1];
            ed[(size_t)row * nheads + hd] = spd[t][0] + spd[t][1];
        }
    }
}

// ---------------------------------------------------------------- GAT agg + LN + relu + residual (heads=4, F=256)
// wave per node; 2 edges/iter (half = lane>>5), lane covers 8 dims (ushort8, 16B),
// 4x manual unroll. Edge weight exp(lrelu()) inline (ed wave-resident, es broadcast
// gather). Residual fp32 (layer1) or bf16 from a DIFFERENT buffer (layer2 ping-pong
// — no in-place read/write aliasing).
__global__ __launch_bounds__(256) void gat_agg_ln_kernel(
    const unsigned short* __restrict__ hb,
    const float* __restrict__ es, const float* __restrict__ ed,
    const int* __restrict__ off, const int* __restrict__ csrs,
    const float* __restrict__ bias, const float* __restrict__ gamma, const float* __restrict__ beta,
    const float* __restrict__ residf, const unsigned short* __restrict__ residb,
    unsigned short* __restrict__ xbout) {
    const int wid = threadIdx.x >> 6, lane = threadIdx.x & 63;
    const int n = blockIdx.x * 4 + wid;
    const int half = lane >> 5, sl = lane & 31;
    const int hd = sl >> 3;            // 8 lanes per head per half
    const int d0 = sl * 8;             // dims d0..d0+7
    const int j0 = off[n], j1 = off[n + 1];
    const float edn = ed[n * HEADS + hd];

    float acc[8] = {};
    float wsum = 0.f;
    int j = j0 + half;
    for (; j + 6 < j1; j += 8) {       // 4 edges per half per iter
        int s0 = csrs[j], s1 = csrs[j + 2], s2 = csrs[j + 4], s3 = csrs[j + 6];
        float w0 = __expf(lrelu(es[s0 * HEADS + hd] + edn));
        float w1 = __expf(lrelu(es[s1 * HEADS + hd] + edn));
        float w2 = __expf(lrelu(es[s2 * HEADS + hd] + edn));
        float w3 = __expf(lrelu(es[s3 * HEADS + hd] + edn));
        u16x8 r0 = *(const u16x8*)(hb + (size_t)s0 * 256 + d0);
        u16x8 r1 = *(const u16x8*)(hb + (size_t)s1 * 256 + d0);
        u16x8 r2 = *(const u16x8*)(hb + (size_t)s2 * 256 + d0);
        u16x8 r3 = *(const u16x8*)(hb + (size_t)s3 * 256 + d0);
        wsum += (w0 + w1) + (w2 + w3);
#pragma unroll
        for (int k = 0; k < 8; k++)
            acc[k] += w0 * bf2f(r0[k]) + w1 * bf2f(r1[k]) + w2 * bf2f(r2[k]) + w3 * bf2f(r3[k]);
    }
    for (; j < j1; j += 2) {
        int s = csrs[j];
        float wt = __expf(lrelu(es[s * HEADS + hd] + edn));
        u16x8 r = *(const u16x8*)(hb + (size_t)s * 256 + d0);
        wsum += wt;
#pragma unroll
        for (int k = 0; k < 8; k++) acc[k] += wt * bf2f(r[k]);
    }
    // combine halves (each half covers the full 256 dims across its 32 lanes)
    wsum += __shfl_xor(wsum, 32);
#pragma unroll
    for (int k = 0; k < 8; k++) acc[k] += __shfl_xor(acc[k], 32);

    float inv = 1.f / (wsum + 1e-16f);
    f32x8 bi = *(const f32x8*)(bias + d0);
    float v[8];
    float ls = 0.f, lq = 0.f;
#pragma unroll
    for (int k = 0; k < 8; k++) {
        v[k] = acc[k] * inv + bi[k];
        ls += v[k];
        lq += v[k] * v[k];
    }
    ls += __shfl_xor(ls, 1);  lq += __shfl_xor(lq, 1);
    ls += __shfl_xor(ls, 2);  lq += __shfl_xor(lq, 2);
    ls += __shfl_xor(ls, 4);  lq += __shfl_xor(lq, 4);
    ls += __shfl_xor(ls, 8);  lq += __shfl_xor(lq, 8);
    ls += __shfl_xor(ls, 16); lq += __shfl_xor(lq, 16);
    float mu = ls * (1.0f / 256.0f);
    float var = lq * (1.0f / 256.0f) - mu * mu;
    float rstd = rsqrtf(var + LN_EPS);
    f32x8 ga = *(const f32x8*)(gamma + d0);
    f32x8 be = *(const f32x8*)(beta + d0);
    // residual loaded by half 0 only; half 1 receives final y via shfl
    f32x8 rs = {};
    if (half == 0) {
        if (residf) {
            rs = *(const f32x8*)(residf + (size_t)n * 256 + d0);
        } else {
            u16x8 rb = *(const u16x8*)(residb + (size_t)n * 256 + d0);
#pragma unroll
            for (int k = 0; k < 8; k++) rs[k] = bf2f(rb[k]);
        }
    }
    float y[8];
#pragma unroll
    for (int k = 0; k < 8; k++) {
        float yy = fmaxf((v[k] - mu) * rstd * ga[k] + be[k], 0.f) + rs[k];
        float tt = __shfl_xor(yy, 32);
        y[k] = half ? tt : yy;
    }
    if (half == 1) {
        u16x8 ob;
#pragma unroll
        for (int k = 0; k < 8; k++) ob[k] = (unsigned short)f2bf(y[k]);
        *(u16x8*)(xbout + (size_t)n * 256 + d0) = ob;
    }
}

// ---------------------------------------------------------------- final GAT (heads=1, F=64) + LN + relu
__global__ __launch_bounds__(256) void gat_final_kernel(
    const unsigned short* __restrict__ hb,
    const float* __restrict__ es, const float* __restrict__ ed,
    const int* __restrict__ off, const int* __restrict__ csrs,
    const float* __restrict__ bias, const float* __restrict__ gamma, const float* __restrict__ beta,
    float* __restrict__ xout) {
    const int wid = threadIdx.x >> 6, lane = threadIdx.x & 63;
    const int n = blockIdx.x * 4 + wid;
    const int q = lane >> 4, sq = lane & 15;
    const int d0 = sq * 4;
    const int j0 = off[n], j1 = off[n + 1];
    const float edn = ed[n];

    float acc[4] = {};
    float wsum = 0.f;
    int j = j0 + q;
    for (; j + 4 < j1; j += 8) {       // 2 edges per quarter per iter
        int s0 = csrs[j], s1 = csrs[j + 4];
        float w0 = __expf(lrelu(es[s0] + edn));
        float w1 = __expf(lrelu(es[s1] + edn));
        ushort4 r0 = *(const ushort4*)(hb + (size_t)s0 * 64 + d0);
        ushort4 r1 = *(const ushort4*)(hb + (size_t)s1 * 64 + d0);
        wsum += w0 + w1;
        acc[0] += w0 * bf2f(r0.x) + w1 * bf2f(r1.x);
        acc[1] += w0 * bf2f(r0.y) + w1 * bf2f(r1.y);
        acc[2] += w0 * bf2f(r0.z) + w1 * bf2f(r1.z);
        acc[3] += w0 * bf2f(r0.w) + w1 * bf2f(r1.w);
    }
    for (; j < j1; j += 4) {
        int s = csrs[j];
        float wt = __expf(lrelu(es[s] + edn));
        ushort4 r = *(const ushort4*)(hb + (size_t)s * 64 + d0);
        wsum += wt;
        acc[0] += wt * bf2f(r.x);
        acc[1] += wt * bf2f(r.y);
        acc[2] += wt * bf2f(r.z);
        acc[3] += wt * bf2f(r.w);
    }
    // combine quarters
    wsum += __shfl_xor(wsum, 16);
    wsum += __shfl_xor(wsum, 32);
#pragma unroll
    for (int k = 0; k < 4; k++) {
        acc[k] += __shfl_xor(acc[k], 16);
        acc[k] += __shfl_xor(acc[k], 32);
    }
    float inv = 1.f / (wsum + 1e-16f);
    float4 bi = *(const float4*)(bias + d0);
    float v[4];
    float ls = 0.f, lq = 0.f;
    v[0] = acc[0] * inv + bi.x; v[1] = acc[1] * inv + bi.y;
    v[2] = acc[2] * inv + bi.z; v[3] = acc[3] * inv + bi.w;
#pragma unroll
    for (int k = 0; k < 4; k++) { ls += v[k]; lq += v[k] * v[k]; }
    ls += __shfl_xor(ls, 1); lq += __shfl_xor(lq, 1);
    ls += __shfl_xor(ls, 2); lq += __shfl_xor(lq, 2);
    ls += __shfl_xor(ls, 4); lq += __shfl_xor(lq, 4);
    ls += __shfl_xor(ls, 8); lq += __shfl_xor(lq, 8);
    float mu = ls * (1.0f / 64.0f);
    float var = lq * (1.0f / 64.0f) - mu * mu;
    float rstd = rsqrtf(var + LN_EPS);
    if (q == 0) {
        float4 ga = *(const float4*)(gamma + d0);
        float4 be = *(const float4*)(beta + d0);
        float4 o;
        o.x = fmaxf((v[0] - mu) * rstd * ga.x + be.x, 0.f);
        o.y = fmaxf((v[1] - mu) * rstd * ga.y + be.y, 0.f);
        o.z = fmaxf((v[2] - mu) * rstd * ga.z + be.z, 0.f);
        o.w = fmaxf((v[3] - mu) * rstd * ga.w + be.w, 0.f);
        *(float4*)(xout + (size_t)n * 64 + d0) = o;
    }
}

// ---------------------------------------------------------------- pooling
__global__ __launch_bounds__(256) void pool_partial_kernel(
    const float* __restrict__ x, const int* __restrict__ gstart,
    float* __restrict__ gsum, unsigned* __restrict__ gmax) {
    int g = blockIdx.x, sp = blockIdx.y;
    int r0 = gstart[g], r1 = gstart[g + 1];
    int t = threadIdx.x, d = t & 63, rg = t >> 6;
    float sum = 0.f, mx = 0.f;
    for (int r = r0 + sp * 4 + rg; r < r1; r += 32) {
        float v = x[(size_t)r * 64 + d];
        sum += v;
        mx = fmaxf(mx, v);
    }
    __shared__ float S[256], M[256];
    S[t] = sum; M[t] = mx;
    __syncthreads();
    if (t < 64) {
        float s4 = S[t] + S[t + 64] + S[t + 128] + S[t + 192];
        float m4 = fmaxf(fmaxf(M[t], M[t + 64]), fmaxf(M[t + 128], M[t + 192]));
        atomicAdd(&gsum[g * 64 + t], s4);
        atomicMax(&gmax[g * 64 + t], __float_as_uint(m4));
    }
}

__global__ void pool_final_kernel(const float* __restrict__ gsum,
                                  const unsigned* __restrict__ gmax,
                                  const int* __restrict__ gstart,
                                  float* __restrict__ pout) {
    int g = blockIdx.x, d = threadIdx.x;
    float c = fmaxf((float)(gstart[g + 1] - gstart[g]), 1.0f);
    pout[g * 128 + d] = gsum[g * 64 + d] / c;
    pout[g * 128 + 64 + d] = __uint_as_float(gmax[g * 64 + d]);
}

// ---------------------------------------------------------------- launch
extern "C" void kernel_launch(void* const* d_in, const int* in_sizes, int n_in,
                              void* d_out, int out_size, void* d_ws, size_t ws_size,
                              hipStream_t stream) {
    const float* node_x = (const float*)d_in[0];
    const int*   ei     = (const int*)d_in[1];
    const int*   batch  = (const int*)d_in[2];
    const float* W1  = (const float*)d_in[3];
    const float* as1 = (const float*)d_in[4];
    const float* ad1 = (const float*)d_in[5];
    const float* b1  = (const float*)d_in[6];
    const float* g1  = (const float*)d_in[7];
    const float* be1 = (const float*)d_in[8];
    const float* W2  = (const float*)d_in[9];
    const float* as2 = (const float*)d_in[10];
    const float* ad2 = (const float*)d_in[11];
    const float* b2  = (const float*)d_in[12];
    const float* g2  = (const float*)d_in[13];
    const float* be2 = (const float*)d_in[14];
    const float* Wf  = (const float*)d_in[15];
    const float* asf = (const float*)d_in[16];
    const float* adf = (const float*)d_in[17];
    const float* bf  = (const float*)d_in[18];
    const float* gf  = (const float*)d_in[19];
    const float* bef = (const float*)d_in[20];
    float* out = (float*)d_out;

    char* w = (char*)d_ws;
    auto alloc = [&](size_t bytes) -> void* {
        void* p = (void*)w;
        w += (bytes + 255) & ~(size_t)255;
        return p;
    };
    unsigned short* hb   = (unsigned short*)alloc((size_t)NN * 256 * 2);  // GEMM bf16 out
    unsigned short* xbA  = (unsigned short*)alloc((size_t)NN * 256 * 2);  // ping
    unsigned short* xbB  = (unsigned short*)alloc((size_t)NN * 256 * 2);  // pong
    short*          wt   = (short*)alloc((size_t)256 * 256 * 2);
    float*          es   = (float*)alloc((size_t)NN * HEADS * 4);
    float*          ed   = (float*)alloc((size_t)NN * HEADS * 4);
    int*      counts = (int*)alloc((size_t)NN * 4);
    int*      off    = (int*)alloc((size_t)(NN + 1) * 4);
    int*      cursor = (int*)alloc((size_t)NN * 4);
    int*      csrs   = (int*)alloc((size_t)TE * 4);
    int*      bsum   = (int*)alloc((size_t)128 * 4);
    int*      boff   = (int*)alloc((size_t)128 * 4);
    float*    gsum   = (float*)alloc((size_t)NG * 64 * 4);
    unsigned* gmax   = (unsigned*)alloc((size_t)NG * 64 * 4);
    int*      gstart = (int*)alloc((size_t)(NG + 1) * 4);

    hipMemsetAsync(counts, 0, (size_t)NN * 4, stream);
    hipMemsetAsync(gsum, 0, (size_t)NG * 64 * 4, stream);
    hipMemsetAsync(gmax, 0, (size_t)NG * 64 * 4, stream);

    const int NB = (NN + 255) / 256;   // 79
    const int EB = (TE + 255) / 256;

    // CSR build
    deg_kernel<<<EB, 256, 0, stream>>>(ei, counts);
    bsum_kernel<<<NB, 256, 0, stream>>>(counts, bsum);
    bscan_kernel<<<1, 128, 0, stream>>>(bsum, boff, NB);
    offsets_kernel<<<NB, 256, 0, stream>>>(counts, boff, off, cursor);
    csr_fill_kernel<<<EB, 256, 0, stream>>>(ei, cursor, csrs);
    gstart_kernel<<<1, 32, 0, stream>>>(batch, gstart);

    const int n4 = NN * 256 / 4;
    dim3 tg256(8, 8), tg64(2, 8);
    dim3 gg256((NN + GBM - 1) / GBM, 256 / GBN);
    dim3 gg64((NN + GBM - 1) / GBM, 1);

    // ---- layer 1 (in: xbA, out: xbB)
    cvt_bf16_kernel<<<(n4 + 255) / 256, 256, 0, stream>>>(node_x, xbA, n4);
    transpose_cvt_kernel<<<tg256, 256, 0, stream>>>(W1, wt, 256, 256);
    gemm_attn_kernel<<<gg256, 256, 0, stream>>>((const short*)xbA, wt, hb, es, ed, as1, ad1, NN, 256, 256, HEADS);
    gat_agg_ln_kernel<<<NN / 4, 256, 0, stream>>>(hb, es, ed, off, csrs, b1, g1, be1, node_x, nullptr, xbB);
    // ---- layer 2 (in: xbB, resid: xbB, out: xbA — distinct read/write buffers)
    transpose_cvt_kernel<<<tg256, 256, 0, stream>>>(W2, wt, 256, 256);
    gemm_attn_kernel<<<gg256, 256, 0, stream>>>((const short*)xbB, wt, hb, es, ed, as2, ad2, NN, 256, 256, HEADS);
    gat_agg_ln_kernel<<<NN / 4, 256, 0, stream>>>(hb, es, ed, off, csrs, b2, g2, be2, nullptr, xbB, xbA);
    // ---- final layer (in: xbA)
    transpose_cvt_kernel<<<tg64, 256, 0, stream>>>(Wf, wt, 256, 64);
    gemm_attn_kernel<<<gg64, 256, 0, stream>>>((const short*)xbA, wt, hb, es, ed, asf, adf, NN, 256, 64, 1);
    gat_final_kernel<<<NN / 4, 256, 0, stream>>>(hb, es, ed, off, csrs, bf, gf, bef, out);
    // ---- pooling
    pool_partial_kernel<<<dim3(NG, 8), 256, 0, stream>>>(out, gstart, gsum, gmax);
    pool_final_kernel<<<NG, 64, 0, stream>>>(gsum, gmax, gstart, out + (size_t)NN * 64);
}

// Round 10
// 275.714 us; speedup vs baseline: 2.9609x; 1.0269x over previous
//
#include <hip/hip_runtime.h>
#include <cstdint>
#include <cstddef>

#define NN 20000
#define EE 320000
#define TE (EE + NN)      // edges + self loops
#define NG 16
#define HEADS 4
#define LN_EPS 1e-5f
#define SLOPE 0.2f

typedef __attribute__((ext_vector_type(8))) short bfx8;
typedef __attribute__((ext_vector_type(8))) unsigned short u16x8;
typedef __attribute__((ext_vector_type(4))) float f32x4;
typedef __attribute__((ext_vector_type(8))) float f32x8;

__device__ __forceinline__ short f2bf(float f) {
    unsigned u = __float_as_uint(f);
    u += 0x7FFFu + ((u >> 16) & 1u);   // RNE
    return (short)(u >> 16);
}
__device__ __forceinline__ float bf2f(unsigned short u) {
    return __uint_as_float(((unsigned)u) << 16);
}
__device__ __forceinline__ float lrelu(float e) {
    return (e >= 0.f) ? e : SLOPE * e;
}

// ---------------------------------------------------------------- CSR build
__global__ void deg_kernel(const int* __restrict__ ei, int* __restrict__ counts) {
    int i = blockIdx.x * blockDim.x + threadIdx.x;
    if (i >= TE) return;
    int d = (i < EE) ? ei[EE + i] : (i - EE);
    atomicAdd(&counts[d], 1);
}

__global__ __launch_bounds__(256) void bsum_kernel(const int* __restrict__ cnt,
                                                   int* __restrict__ bsum) {
    int b = blockIdx.x;
    int i = b * 256 + threadIdx.x;
    int v = (i < NN) ? cnt[i] : 0;
    for (int s = 32; s > 0; s >>= 1) v += __shfl_down(v, s);
    __shared__ int ws4[4];
    int lane = threadIdx.x & 63, w = threadIdx.x >> 6;
    if (lane == 0) ws4[w] = v;
    __syncthreads();
    if (threadIdx.x == 0) bsum[b] = ws4[0] + ws4[1] + ws4[2] + ws4[3];
}

__global__ void bscan_kernel(const int* __restrict__ bsum, int* __restrict__ boff, int nb) {
    __shared__ int s[128];
    int t = threadIdx.x;
    int v = (t < nb) ? bsum[t] : 0;
    s[t] = v;
    __syncthreads();
    for (int st = 1; st < 128; st <<= 1) {
        int a = (t >= st) ? s[t - st] : 0;
        __syncthreads();
        s[t] += a;
        __syncthreads();
    }
    if (t < nb) boff[t] = s[t] - v;   // exclusive
}

__global__ __launch_bounds__(256) void offsets_kernel(const int* __restrict__ cnt,
                                                      const int* __restrict__ boff,
                                                      int* __restrict__ off,
                                                      int* __restrict__ cursor) {
    int b = blockIdx.x, t = threadIdx.x;
    int i = b * 256 + t;
    int v = (i < NN) ? cnt[i] : 0;
    int lane = t & 63, w = t >> 6;
    int x = v;
    for (int s = 1; s < 64; s <<= 1) {
        int u = __shfl_up(x, s);
        if (lane >= s) x += u;
    }
    __shared__ int wsum[4];
    if (lane == 63) wsum[w] = x;
    __syncthreads();
    int pre = 0;
    for (int k = 0; k < w; k++) pre += wsum[k];
    int excl = (x + pre - v) + boff[b];
    if (i < NN) { cursor[i] = excl; off[i] = excl; }
    if (i == NN - 1) off[NN] = excl + v;
}

__global__ void csr_fill_kernel(const int* __restrict__ ei, int* __restrict__ cursor,
                                int* __restrict__ csr_src) {
    int i = blockIdx.x * blockDim.x + threadIdx.x;
    if (i >= TE) return;
    int s, d;
    if (i < EE) { s = ei[i]; d = ei[EE + i]; }
    else        { s = i - EE; d = s; }
    int pos = atomicAdd(&cursor[d], 1);
    csr_src[pos] = s;
}

// batch sorted -> binary search, no atomics
__global__ void gstart_kernel(const int* __restrict__ batch, int* __restrict__ gstart) {
    int g = threadIdx.x;
    if (g > NG) return;
    int lo = 0, hi = NN;
    while (lo < hi) {
        int mid = (lo + hi) >> 1;
        if (batch[mid] < g) lo = mid + 1; else hi = mid;
    }
    gstart[g] = lo;
}

// ---------------------------------------------------------------- weight prep: all 3 W^T in one launch
// z=0: W1[256x256]->wt1, z=1: W2[256x256]->wt2, z=2: Wf[256x64]->wtf. K=256 rows for all.
__global__ __launch_bounds__(256) void transpose_all_kernel(
    const float* __restrict__ W1, const float* __restrict__ W2, const float* __restrict__ Wf,
    short* __restrict__ wt1, short* __restrict__ wt2, short* __restrict__ wtf) {
    __shared__ float tile[32][33];
    int z = blockIdx.z;
    const float* W = (z == 0) ? W1 : (z == 1) ? W2 : Wf;
    short* WT = (z == 0) ? wt1 : (z == 1) ? wt2 : wtf;
    int Nc = (z == 2) ? 64 : 256;
    int bx = blockIdx.x * 32;   // n base
    int by = blockIdx.y * 32;   // k base
    if (bx >= Nc) return;
    int tx = threadIdx.x & 31, ty = threadIdx.x >> 5;
    for (int r = ty; r < 32; r += 8)
        tile[r][tx] = W[(size_t)(by + r) * Nc + bx + tx];
    __syncthreads();
    for (int r = ty; r < 32; r += 8)
        WT[(size_t)(bx + r) * 256 + by + tx] = f2bf(tile[tx][r]);
}

// ---------------------------------------------------------------- GEMM (bf16 MFMA) + fused attention scores
// A either fp32 (layer 1: converted RNE during staging, bit-identical to pre-cvt) or bf16.
// grid = (Nc/64, M/64): column-siblings of one A-row-panel are dispatch-adjacent (L2 A-reuse).
#define GBM 64
#define GBN 64
#define GBK 64
template<bool AF32>
__global__ __launch_bounds__(256) void gemm_attn_kernel(const void* __restrict__ Ap,
                                                        const short* __restrict__ BT,
                                                        unsigned short* __restrict__ Cb,
                                                        float* __restrict__ es,
                                                        float* __restrict__ ed,
                                                        const float* __restrict__ av_src,
                                                        const float* __restrict__ av_dst,
                                                        int M, int K, int Nc, int nheads) {
    __shared__ short Al[GBM * GBK];
    __shared__ short Bl[GBN * GBK];
    __shared__ float sps[64][2];
    __shared__ float spd[64][2];
    const int t = threadIdx.x;
    const int lane = t & 63, wid = t >> 6;
    const int wr = (wid >> 1) * 32, wc = (wid & 1) * 32;
    const int bm = blockIdx.y * GBM, bn = blockIdx.x * GBN;   // swapped vs R9
    const int r0 = t >> 3, ch = t & 7;

    f32x4 acc[2][2] = {};

    for (int k0 = 0; k0 < K; k0 += GBK) {
#pragma unroll
        for (int p = 0; p < 2; p++) {
            int row = p * 32 + r0;
            int arow = bm + row; if (arow >= M) arow = M - 1;
            bfx8 av;
            if constexpr (AF32) {
                const float* A = (const float*)Ap;
                const float* src = A + (size_t)arow * K + k0 + ch * 8;
                float4 f0 = *(const float4*)(src);
                float4 f1 = *(const float4*)(src + 4);
                av[0] = f2bf(f0.x); av[1] = f2bf(f0.y); av[2] = f2bf(f0.z); av[3] = f2bf(f0.w);
                av[4] = f2bf(f1.x); av[5] = f2bf(f1.y); av[6] = f2bf(f1.z); av[7] = f2bf(f1.w);
            } else {
                const short* A = (const short*)Ap;
                av = *(const bfx8*)(A + (size_t)arow * K + k0 + ch * 8);
            }
            bfx8 bv = *(const bfx8*)(BT + (size_t)(bn + row) * K + k0 + ch * 8);
            int wo = (row << 7) + (((ch ^ (row & 7))) << 4);
            *(bfx8*)((char*)Al + wo) = av;
            *(bfx8*)((char*)Bl + wo) = bv;
        }
        __syncthreads();
        bfx8 af[2][2], bfm[2][2];
#pragma unroll
        for (int m = 0; m < 2; m++)
#pragma unroll
            for (int kk = 0; kk < 2; kk++) {
                int rowa = wr + m * 16 + (lane & 15);
                int rowb = wc + m * 16 + (lane & 15);
                int c = kk * 4 + (lane >> 4);
                af[m][kk]  = *(const bfx8*)((const char*)Al + (rowa << 7) + (((c ^ (rowa & 7))) << 4));
                bfm[m][kk] = *(const bfx8*)((const char*)Bl + (rowb << 7) + (((c ^ (rowb & 7))) << 4));
            }
#pragma unroll
        for (int m = 0; m < 2; m++)
#pragma unroll
            for (int n = 0; n < 2; n++) {
                acc[m][n] = __builtin_amdgcn_mfma_f32_16x16x32_bf16(af[m][0], bfm[n][0], acc[m][n], 0, 0, 0);
                acc[m][n] = __builtin_amdgcn_mfma_f32_16x16x32_bf16(af[m][1], bfm[n][1], acc[m][n], 0, 0, 0);
            }
        __syncthreads();
    }

    // ---- store bf16 output
#pragma unroll
    for (int m = 0; m < 2; m++) {
        int row0 = bm + wr + m * 16 + ((lane >> 4) << 2);
#pragma unroll
        for (int n = 0; n < 2; n++) {
            int col = bn + wc + n * 16 + (lane & 15);
#pragma unroll
            for (int j = 0; j < 4; j++) {
                int row = row0 + j;
                if (row < M) Cb[(size_t)row * Nc + col] = (unsigned short)f2bf(acc[m][n][j]);
            }
        }
    }

    // ---- fused attention scores: es/ed[row, head]
    const int hd = bn >> 6;
    float asv[2], adv[2];
#pragma unroll
    for (int n = 0; n < 2; n++) {
        int c = wc + n * 16 + (lane & 15);   // dim within head (0..63)
        asv[n] = av_src[hd * 64 + c];
        adv[n] = av_dst[hd * 64 + c];
    }
#pragma unroll
    for (int m = 0; m < 2; m++) {
#pragma unroll
        for (int j = 0; j < 4; j++) {
            float ps = acc[m][0][j] * asv[0] + acc[m][1][j] * asv[1];
            float pd = acc[m][0][j] * adv[0] + acc[m][1][j] * adv[1];
            ps += __shfl_xor(ps, 1); pd += __shfl_xor(pd, 1);
            ps += __shfl_xor(ps, 2); pd += __shfl_xor(pd, 2);
            ps += __shfl_xor(ps, 4); pd += __shfl_xor(pd, 4);
            ps += __shfl_xor(ps, 8); pd += __shfl_xor(pd, 8);
            if ((lane & 15) == 0) {
                int rl = wr + m * 16 + ((lane >> 4) << 2) + j;
                sps[rl][wid & 1] = ps;
                spd[rl][wid & 1] = pd;
            }
        }
    }
    __syncthreads();
    if (t < 64) {
        int row = bm + t;
        if (row < M) {
            es[(size_t)row * nheads + hd] = sps[t][0] + sps[t][1];
            ed[(size_t)row * nheads + hd] = spd[t][0] + spd[t][1];
        }
    }
}

// ---------------------------------------------------------------- GAT agg + LN + relu + residual (heads=4, F=256)
__global__ __launch_bounds__(256) void gat_agg_ln_kernel(
    const unsigned short* __restrict__ hb,
    const float* __restrict__ es, const float* __restrict__ ed,
    const int* __restrict__ off, const int* __restrict__ csrs,
    const float* __restrict__ bias, const float* __restrict__ gamma, const float* __restrict__ beta,
    const float* __restrict__ residf, const unsigned short* __restrict__ residb,
    unsigned short* __restrict__ xbout) {
    const int wid = threadIdx.x >> 6, lane = threadIdx.x & 63;
    const int n = blockIdx.x * 4 + wid;
    const int half = lane >> 5, sl = lane & 31;
    const int hd = sl >> 3;            // 8 lanes per head per half
    const int d0 = sl * 8;             // dims d0..d0+7
    const int j0 = off[n], j1 = off[n + 1];
    const float edn = ed[n * HEADS + hd];

    float acc[8] = {};
    float wsum = 0.f;
    int j = j0 + half;
    for (; j + 6 < j1; j += 8) {       // 4 edges per half per iter
        int s0 = csrs[j], s1 = csrs[j + 2], s2 = csrs[j + 4], s3 = csrs[j + 6];
        float w0 = __expf(lrelu(es[s0 * HEADS + hd] + edn));
        float w1 = __expf(lrelu(es[s1 * HEADS + hd] + edn));
        float w2 = __expf(lrelu(es[s2 * HEADS + hd] + edn));
        float w3 = __expf(lrelu(es[s3 * HEADS + hd] + edn));
        u16x8 r0 = *(const u16x8*)(hb + (size_t)s0 * 256 + d0);
        u16x8 r1 = *(const u16x8*)(hb + (size_t)s1 * 256 + d0);
        u16x8 r2 = *(const u16x8*)(hb + (size_t)s2 * 256 + d0);
        u16x8 r3 = *(const u16x8*)(hb + (size_t)s3 * 256 + d0);
        wsum += (w0 + w1) + (w2 + w3);
#pragma unroll
        for (int k = 0; k < 8; k++)
            acc[k] += w0 * bf2f(r0[k]) + w1 * bf2f(r1[k]) + w2 * bf2f(r2[k]) + w3 * bf2f(r3[k]);
    }
    for (; j < j1; j += 2) {
        int s = csrs[j];
        float wt = __expf(lrelu(es[s * HEADS + hd] + edn));
        u16x8 r = *(const u16x8*)(hb + (size_t)s * 256 + d0);
        wsum += wt;
#pragma unroll
        for (int k = 0; k < 8; k++) acc[k] += wt * bf2f(r[k]);
    }
    // combine halves (each half covers the full 256 dims across its 32 lanes)
    wsum += __shfl_xor(wsum, 32);
#pragma unroll
    for (int k = 0; k < 8; k++) acc[k] += __shfl_xor(acc[k], 32);

    float inv = 1.f / (wsum + 1e-16f);
    f32x8 bi = *(const f32x8*)(bias + d0);
    float v[8];
    float ls = 0.f, lq = 0.f;
#pragma unroll
    for (int k = 0; k < 8; k++) {
        v[k] = acc[k] * inv + bi[k];
        ls += v[k];
        lq += v[k] * v[k];
    }
    ls += __shfl_xor(ls, 1);  lq += __shfl_xor(lq, 1);
    ls += __shfl_xor(ls, 2);  lq += __shfl_xor(lq, 2);
    ls += __shfl_xor(ls, 4);  lq += __shfl_xor(lq, 4);
    ls += __shfl_xor(ls, 8);  lq += __shfl_xor(lq, 8);
    ls += __shfl_xor(ls, 16); lq += __shfl_xor(lq, 16);
    float mu = ls * (1.0f / 256.0f);
    float var = lq * (1.0f / 256.0f) - mu * mu;
    float rstd = rsqrtf(var + LN_EPS);
    f32x8 ga = *(const f32x8*)(gamma + d0);
    f32x8 be = *(const f32x8*)(beta + d0);
    // residual loaded by half 0 only; half 1 receives final y via shfl
    f32x8 rs = {};
    if (half == 0) {
        if (residf) {
            rs = *(const f32x8*)(residf + (size_t)n * 256 + d0);
        } else {
            u16x8 rb = *(const u16x8*)(residb + (size_t)n * 256 + d0);
#pragma unroll
            for (int k = 0; k < 8; k++) rs[k] = bf2f(rb[k]);
        }
    }
    float y[8];
#pragma unroll
    for (int k = 0; k < 8; k++) {
        float yy = fmaxf((v[k] - mu) * rstd * ga[k] + be[k], 0.f) + rs[k];
        float tt = __shfl_xor(yy, 32);
        y[k] = half ? tt : yy;
    }
    if (half == 1) {
        u16x8 ob;
#pragma unroll
        for (int k = 0; k < 8; k++) ob[k] = (unsigned short)f2bf(y[k]);
        *(u16x8*)(xbout + (size_t)n * 256 + d0) = ob;
    }
}

// ---------------------------------------------------------------- final GAT (heads=1, F=64) + LN + relu
__global__ __launch_bounds__(256) void gat_final_kernel(
    const unsigned short* __restrict__ hb,
    const float* __restrict__ es, const float* __restrict__ ed,
    const int* __restrict__ off, const int* __restrict__ csrs,
    const float* __restrict__ bias, const float* __restrict__ gamma, const float* __restrict__ beta,
    float* __restrict__ xout) {
    const int wid = threadIdx.x >> 6, lane = threadIdx.x & 63;
    const int n = blockIdx.x * 4 + wid;
    const int q = lane >> 4, sq = lane & 15;
    const int d0 = sq * 4;
    const int j0 = off[n], j1 = off[n + 1];
    const float edn = ed[n];

    float acc[4] = {};
    float wsum = 0.f;
    int j = j0 + q;
    for (; j + 4 < j1; j += 8) {       // 2 edges per quarter per iter
        int s0 = csrs[j], s1 = csrs[j + 4];
        float w0 = __expf(lrelu(es[s0] + edn));
        float w1 = __expf(lrelu(es[s1] + edn));
        ushort4 r0 = *(const ushort4*)(hb + (size_t)s0 * 64 + d0);
        ushort4 r1 = *(const ushort4*)(hb + (size_t)s1 * 64 + d0);
        wsum += w0 + w1;
        acc[0] += w0 * bf2f(r0.x) + w1 * bf2f(r1.x);
        acc[1] += w0 * bf2f(r0.y) + w1 * bf2f(r1.y);
        acc[2] += w0 * bf2f(r0.z) + w1 * bf2f(r1.z);
        acc[3] += w0 * bf2f(r0.w) + w1 * bf2f(r1.w);
    }
    for (; j < j1; j += 4) {
        int s = csrs[j];
        float wt = __expf(lrelu(es[s] + edn));
        ushort4 r = *(const ushort4*)(hb + (size_t)s * 64 + d0);
        wsum += wt;
        acc[0] += wt * bf2f(r.x);
        acc[1] += wt * bf2f(r.y);
        acc[2] += wt * bf2f(r.z);
        acc[3] += wt * bf2f(r.w);
    }
    // combine quarters
    wsum += __shfl_xor(wsum, 16);
    wsum += __shfl_xor(wsum, 32);
#pragma unroll
    for (int k = 0; k < 4; k++) {
        acc[k] += __shfl_xor(acc[k], 16);
        acc[k] += __shfl_xor(acc[k], 32);
    }
    float inv = 1.f / (wsum + 1e-16f);
    float4 bi = *(const float4*)(bias + d0);
    float v[4];
    float ls = 0.f, lq = 0.f;
    v[0] = acc[0] * inv + bi.x; v[1] = acc[1] * inv + bi.y;
    v[2] = acc[2] * inv + bi.z; v[3] = acc[3] * inv + bi.w;
#pragma unroll
    for (int k = 0; k < 4; k++) { ls += v[k]; lq += v[k] * v[k]; }
    ls += __shfl_xor(ls, 1); lq += __shfl_xor(lq, 1);
    ls += __shfl_xor(ls, 2); lq += __shfl_xor(lq, 2);
    ls += __shfl_xor(ls, 4); lq += __shfl_xor(lq, 4);
    ls += __shfl_xor(ls, 8); lq += __shfl_xor(lq, 8);
    float mu = ls * (1.0f / 64.0f);
    float var = lq * (1.0f / 64.0f) - mu * mu;
    float rstd = rsqrtf(var + LN_EPS);
    if (q == 0) {
        float4 ga = *(const float4*)(gamma + d0);
        float4 be = *(const float4*)(beta + d0);
        float4 o;
        o.x = fmaxf((v[0] - mu) * rstd * ga.x + be.x, 0.f);
        o.y = fmaxf((v[1] - mu) * rstd * ga.y + be.y, 0.f);
        o.z = fmaxf((v[2] - mu) * rstd * ga.z + be.z, 0.f);
        o.w = fmaxf((v[3] - mu) * rstd * ga.w + be.w, 0.f);
        *(float4*)(xout + (size_t)n * 64 + d0) = o;
    }
}

// ---------------------------------------------------------------- pooling
__global__ __launch_bounds__(256) void pool_partial_kernel(
    const float* __restrict__ x, const int* __restrict__ gstart,
    float* __restrict__ gsum, unsigned* __restrict__ gmax) {
    int g = blockIdx.x, sp = blockIdx.y;
    int r0 = gstart[g], r1 = gstart[g + 1];
    int t = threadIdx.x, d = t & 63, rg = t >> 6;
    float sum = 0.f, mx = 0.f;
    for (int r = r0 + sp * 4 + rg; r < r1; r += 32) {
        float v = x[(size_t)r * 64 + d];
        sum += v;
        mx = fmaxf(mx, v);
    }
    __shared__ float S[256], M[256];
    S[t] = sum; M[t] = mx;
    __syncthreads();
    if (t < 64) {
        float s4 = S[t] + S[t + 64] + S[t + 128] + S[t + 192];
        float m4 = fmaxf(fmaxf(M[t], M[t + 64]), fmaxf(M[t + 128], M[t + 192]));
        atomicAdd(&gsum[g * 64 + t], s4);
        atomicMax(&gmax[g * 64 + t], __float_as_uint(m4));
    }
}

__global__ void pool_final_kernel(const float* __restrict__ gsum,
                                  const unsigned* __restrict__ gmax,
                                  const int* __restrict__ gstart,
                                  float* __restrict__ pout) {
    int g = blockIdx.x, d = threadIdx.x;
    float c = fmaxf((float)(gstart[g + 1] - gstart[g]), 1.0f);
    pout[g * 128 + d] = gsum[g * 64 + d] / c;
    pout[g * 128 + 64 + d] = __uint_as_float(gmax[g * 64 + d]);
}

// ---------------------------------------------------------------- launch
extern "C" void kernel_launch(void* const* d_in, const int* in_sizes, int n_in,
                              void* d_out, int out_size, void* d_ws, size_t ws_size,
                              hipStream_t stream) {
    const float* node_x = (const float*)d_in[0];
    const int*   ei     = (const int*)d_in[1];
    const int*   batch  = (const int*)d_in[2];
    const float* W1  = (const float*)d_in[3];
    const float* as1 = (const float*)d_in[4];
    const float* ad1 = (const float*)d_in[5];
    const float* b1  = (const float*)d_in[6];
    const float* g1  = (const float*)d_in[7];
    const float* be1 = (const float*)d_in[8];
    const float* W2  = (const float*)d_in[9];
    const float* as2 = (const float*)d_in[10];
    const float* ad2 = (const float*)d_in[11];
    const float* b2  = (const float*)d_in[12];
    const float* g2  = (const float*)d_in[13];
    const float* be2 = (const float*)d_in[14];
    const float* Wf  = (const float*)d_in[15];
    const float* asf = (const float*)d_in[16];
    const float* adf = (const float*)d_in[17];
    const float* bf  = (const float*)d_in[18];
    const float* gf  = (const float*)d_in[19];
    const float* bef = (const float*)d_in[20];
    float* out = (float*)d_out;

    char* w = (char*)d_ws;
    auto alloc = [&](size_t bytes) -> void* {
        void* p = (void*)w;
        w += (bytes + 255) & ~(size_t)255;
        return p;
    };
    unsigned short* hb   = (unsigned short*)alloc((size_t)NN * 256 * 2);  // GEMM bf16 out
    unsigned short* xbA  = (unsigned short*)alloc((size_t)NN * 256 * 2);  // ping (layer-2 agg out)
    unsigned short* xbB  = (unsigned short*)alloc((size_t)NN * 256 * 2);  // pong (layer-1 agg out)
    short*          wt1  = (short*)alloc((size_t)256 * 256 * 2);
    short*          wt2  = (short*)alloc((size_t)256 * 256 * 2);
    short*          wtf  = (short*)alloc((size_t)64 * 256 * 2);
    float*          es   = (float*)alloc((size_t)NN * HEADS * 4);
    float*          ed   = (float*)alloc((size_t)NN * HEADS * 4);
    int*      counts = (int*)alloc((size_t)NN * 4);
    int*      off    = (int*)alloc((size_t)(NN + 1) * 4);
    int*      cursor = (int*)alloc((size_t)NN * 4);
    int*      csrs   = (int*)alloc((size_t)TE * 4);
    int*      bsum   = (int*)alloc((size_t)128 * 4);
    int*      boff   = (int*)alloc((size_t)128 * 4);
    float*    gsum   = (float*)alloc((size_t)NG * 64 * 4);
    unsigned* gmax   = (unsigned*)alloc((size_t)NG * 64 * 4);
    int*      gstart = (int*)alloc((size_t)(NG + 1) * 4);

    hipMemsetAsync(counts, 0, (size_t)NN * 4, stream);
    hipMemsetAsync(gsum, 0, (size_t)NG * 64 * 4, stream);
    hipMemsetAsync(gmax, 0, (size_t)NG * 64 * 4, stream);

    const int NB = (NN + 255) / 256;   // 79
    const int EB = (TE + 255) / 256;

    // CSR build
    deg_kernel<<<EB, 256, 0, stream>>>(ei, counts);
    bsum_kernel<<<NB, 256, 0, stream>>>(counts, bsum);
    bscan_kernel<<<1, 128, 0, stream>>>(bsum, boff, NB);
    offsets_kernel<<<NB, 256, 0, stream>>>(counts, boff, off, cursor);
    csr_fill_kernel<<<EB, 256, 0, stream>>>(ei, cursor, csrs);
    gstart_kernel<<<1, 32, 0, stream>>>(batch, gstart);

    // all weight transposes in one launch
    transpose_all_kernel<<<dim3(8, 8, 3), 256, 0, stream>>>(W1, W2, Wf, wt1, wt2, wtf);

    dim3 gg256(4, (NN + GBM - 1) / GBM);   // column-siblings adjacent
    dim3 gg64(1, (NN + GBM - 1) / GBM);

    // ---- layer 1 (A = node_x fp32, converted in staging; out: xbB)
    gemm_attn_kernel<true><<<gg256, 256, 0, stream>>>(node_x, wt1, hb, es, ed, as1, ad1, NN, 256, 256, HEADS);
    gat_agg_ln_kernel<<<NN / 4, 256, 0, stream>>>(hb, es, ed, off, csrs, b1, g1, be1, node_x, nullptr, xbB);
    // ---- layer 2 (in: xbB, resid: xbB, out: xbA — distinct buffers)
    gemm_attn_kernel<false><<<gg256, 256, 0, stream>>>(xbB, wt2, hb, es, ed, as2, ad2, NN, 256, 256, HEADS);
    gat_agg_ln_kernel<<<NN / 4, 256, 0, stream>>>(hb, es, ed, off, csrs, b2, g2, be2, nullptr, xbB, xbA);
    // ---- final layer (in: xbA)
    gemm_attn_kernel<false><<<gg64, 256, 0, stream>>>(xbA, wtf, hb, es, ed, asf, adf, NN, 256, 64, 1);
    gat_final_kernel<<<NN / 4, 256, 0, stream>>>(hb, es, ed, off, csrs, bf, gf, bef, out);
    // ---- pooling
    pool_partial_kernel<<<dim3(NG, 8), 256, 0, stream>>>(out, gstart, gsum, gmax);
    pool_final_kernel<<<NG, 64, 0, stream>>>(gsum, gmax, gstart, out + (size_t)NN * 64);
}